// Round 17
// baseline (259.836 us; speedup 1.0000x reference)
//
#include <hip/hip_runtime.h>
#include <math.h>

#define NN 4000
#define EE 40000
#define NE 44000   // EE + NN self-loops
#define BB 2
#define TT 8
#define BT 16      // B*T graph instances
#define HH 4
#define CC 64
#define HC 256     // H*C
#define HLN 128    // lstm hidden
#define G4 512     // 4*HLN
#define FHN 128
#define ROWSL 16   // lstm rows per block
#define PADU 136   // ushort pad for h LDS rows
#define PADC 196   // fp32 pad for cat LDS rows

typedef __attribute__((ext_vector_type(8))) short short8v;
typedef __attribute__((ext_vector_type(4))) float f32x4;

__device__ __forceinline__ float fexp2(float x){ return __builtin_amdgcn_exp2f(x); }
__device__ __forceinline__ float frcp(float x){ return __builtin_amdgcn_rcpf(x); }
__device__ __forceinline__ float fsig(float x){ return frcp(1.f + fexp2(x * -1.44269504f)); }
__device__ __forceinline__ float ftanh(float x){
  float xx = fminf(fmaxf(x, -10.f), 10.f);
  float e = fexp2(xx * 2.88539008f);
  return (e - 1.f) * frcp(e + 1.f);
}
__device__ __forceinline__ unsigned short bf16rne(float x){
  unsigned u = __float_as_uint(x);
  return (unsigned short)((u + 0x7FFFu + ((u>>16)&1u)) >> 16);
}
__device__ __forceinline__ float bf2f(unsigned short h){ return __uint_as_float(((unsigned)h)<<16); }

// ---------------- CSR build (deterministic: atomic scatter + per-segment sort) ----------------
__global__ void k_count(const int* __restrict__ dst, int* __restrict__ cnt){
  int e = blockIdx.x*256+threadIdx.x;
  if (e >= NE) return;
  int d = (e < EE) ? dst[e] : (e - EE);
  atomicAdd(&cnt[d], 1);
}

__global__ __launch_bounds__(1024) void k_scan(const int* __restrict__ cnt, int* __restrict__ ptr){
  __shared__ int part[1024];
  const int n = NN;
  int t = threadIdx.x;
  int base = t*4;
  int loc[4]; int s = 0;
  #pragma unroll
  for (int i=0;i<4;i++){ int c = (base+i < n) ? cnt[base+i] : 0; loc[i] = s; s += c; }
  part[t] = s;
  __syncthreads();
  for (int off=1; off<1024; off<<=1){
    int add = (t >= off) ? part[t-off] : 0;
    __syncthreads();
    part[t] += add;
    __syncthreads();
  }
  int ebase = (t > 0) ? part[t-1] : 0;
  #pragma unroll
  for (int i=0;i<4;i++){ if (base+i < n) ptr[base+i] = ebase + loc[i]; }
  if (t == 1023) ptr[n] = part[1023];
}

__global__ void k_scatter(const int* __restrict__ dst, const int* __restrict__ ptr,
                          int* __restrict__ cur, int* __restrict__ idxa){
  int e = blockIdx.x*256+threadIdx.x;
  if (e >= NE) return;
  int d = (e < EE) ? dst[e] : (e - EE);
  int pos = atomicAdd(&cur[d], 1);
  idxa[ptr[d]+pos] = e;
}

// sort each segment (deterministic order) and emit position-indexed src
__global__ void k_sortseg(const int* __restrict__ ptr, int* __restrict__ idxa,
                          const int* __restrict__ e0, int* __restrict__ srcs){
  int node = blockIdx.x*256+threadIdx.x;
  if (node >= NN) return;
  int p0 = ptr[node], p1 = ptr[node+1];
  for (int i=p0+1;i<p1;i++){
    int key = idxa[i]; int j = i-1;
    while (j >= p0 && idxa[j] > key){ idxa[j+1] = idxa[j]; j--; }
    idxa[j+1] = key;
  }
  for (int p=p0;p<p1;p++){
    int e = idxa[p];
    srcs[p] = (e < EE) ? e0[e] : (e - EE);
  }
}

// ------- merged prep: zero cnt | wtilde | LSTM frags | WfT | GAT Wb frags (bf16 hi/lo) ----------
__global__ void k_prep(int* __restrict__ cnt,
                       const float* __restrict__ W1, const float* __restrict__ as1, const float* __restrict__ ad1,
                       const float* __restrict__ W2, const float* __restrict__ as2, const float* __restrict__ ad2,
                       float* __restrict__ wt,
                       const float* __restrict__ Wih, const float* __restrict__ Whh,
                       unsigned short* __restrict__ wfh, unsigned short* __restrict__ wfl,
                       const float* __restrict__ Wf, float* __restrict__ WfT,
                       unsigned short* __restrict__ wb1h, unsigned short* __restrict__ wb1l,
                       unsigned short* __restrict__ wb2h, unsigned short* __restrict__ wb2l){
  int i = blockIdx.x*256 + threadIdx.x;
  if (i < 2*NN){ cnt[i] = 0; return; }
  i -= 2*NN;
  if (i < 768){
    if (i < 256){                      // layer1 wtilde: sd*128 + h*32 + k
      int sd = i >> 7, h = (i >> 5) & 3, k = i & 31;
      const float* a = sd ? ad1 : as1;
      float s = 0.f;
      for (int c=0;c<CC;c++) s = fmaf(W1[k*HC + h*CC + c], a[h*CC + c], s);
      wt[sd*128 + h*32 + k] = s;
    } else {
      int j = i - 256;
      int sd = j >> 8, h = (j >> 6) & 3, k = j & 63;
      const float* a = sd ? ad2 : as2;
      float s = 0.f;
      for (int c=0;c<CC;c++) s = fmaf(W2[k*HC + h*CC + c], a[h*CC + c], s);
      wt[256 + sd*256 + h*64 + k] = s;
    }
    return;
  }
  i -= 768;
  if (i < 12288){                      // LSTM B-fragments (bf16 hi/lo split)
    int lane = i & 63;
    int kc = (i >> 6) % 6;
    int wk = i / (64*6);
    int w = wk & 7, gg = wk >> 3;
    int n = gg*128 + w*16 + (lane & 15);
    int kbase = kc*32 + (lane >> 4)*8;
    #pragma unroll
    for (int j=0;j<8;j++){
      int k = kbase + j;
      float v = (k < 64) ? Wih[n*64 + k] : Whh[n*128 + (k-64)];
      unsigned short hi = bf16rne(v);
      wfh[(size_t)i*8 + j] = hi;
      wfl[(size_t)i*8 + j] = bf16rne(v - bf2f(hi));
    }
    return;
  }
  i -= 12288;
  if (i < 24576){                      // WfT[u][k] = Wf[k][u]
    int u = i & 127, k = i >> 7;
    WfT[u*192 + k] = Wf[k*128 + u];
    return;
  }
  i -= 24576;
  if (i < 1024){                       // layer1 Wb frags: (nt*4 + kc)*64 + lane, KF=32
    int lane = i & 63, kc = (i >> 6) & 3, nt = i >> 8;
    int n = nt*16 + (lane & 15);
    int kb = kc*32 + (lane >> 4)*8;
    #pragma unroll
    for (int j=0;j<8;j++){
      int k = kb + j; int h = k >> 5; int kk = k & 31;
      float v = W1[kk*HC + h*CC + n];
      unsigned short hi = bf16rne(v);
      wb1h[(size_t)i*8 + j] = hi;
      wb1l[(size_t)i*8 + j] = bf16rne(v - bf2f(hi));
    }
    return;
  }
  i -= 1024;
  if (i < 2048){                       // layer2 Wb frags: (nt*8 + kc)*64 + lane, KF=64
    int lane = i & 63, kc = (i >> 6) & 7, nt = i >> 9;
    int n = nt*16 + (lane & 15);
    int kb = kc*32 + (lane >> 4)*8;
    #pragma unroll
    for (int j=0;j<8;j++){
      int k = kb + j; int h = k >> 6; int kk = k & 63;
      float v = W2[kk*HC + h*CC + n];
      unsigned short hi = bf16rne(v);
      wb2h[(size_t)i*8 + j] = hi;
      wb2l[(size_t)i*8 + j] = bf16rne(v - bf2f(hi));
    }
  }
}

// ---------------- attention coefficients: one thread per (inst,node), all 4 heads ----------------
template<int K>
__global__ void k_coef3(const float* __restrict__ x, const float* __restrict__ wts,
                        const float* __restrict__ wtd,
                        float* __restrict__ als, float* __restrict__ ald){
  int i = blockIdx.x*256+threadIdx.x;          // inst*NN + n
  if (i >= BT*NN) return;
  const float* xp = x + (size_t)i*K;
  float s1[4] = {0.f,0.f,0.f,0.f};
  float s2[4] = {0.f,0.f,0.f,0.f};
  for (int k=0;k<K;k+=4){
    float4 xv = *(const float4*)&xp[k];
    #pragma unroll
    for (int h=0;h<4;h++){
      float4 sv = *(const float4*)&wts[h*K+k];
      float4 dv = *(const float4*)&wtd[h*K+k];
      s1[h] = fmaf(xv.x,sv.x,fmaf(xv.y,sv.y,fmaf(xv.z,sv.z,fmaf(xv.w,sv.w,s1[h]))));
      s2[h] = fmaf(xv.x,dv.x,fmaf(xv.y,dv.y,fmaf(xv.z,dv.z,fmaf(xv.w,dv.w,s2[h]))));
    }
  }
  *(float4*)&als[(size_t)i*4] = make_float4(s1[0],s1[1],s1[2],s1[3]);
  *(float4*)&ald[(size_t)i*4] = make_float4(s2[0],s2[1],s2[2],s2[3]);
}

// ---- fused GAT layer v6: 16-lane group per node, 2-edge unrolled gather loop, MFMA GEMM ---------
template<int KF, bool SPLIT>
__global__ __launch_bounds__(256) void k_gatt(const int* __restrict__ ptr, const int* __restrict__ srcs,
    const float* __restrict__ als, const float* __restrict__ ald, const float* __restrict__ xin,
    const unsigned short* __restrict__ wbh, const unsigned short* __restrict__ wbl,
    const float* __restrict__ bias, float* __restrict__ outp,
    unsigned short* __restrict__ ohi, unsigned short* __restrict__ olo){
  constexpr int K = HH*KF;            // 128 / 256
  constexpr int PR = K + 8;           // padded row in ushorts
  constexpr int NKC = K/32;           // 4 / 8
  constexpr int VPL = KF/16;          // floats per lane: 2 (KF=32) or 4 (KF=64)
  __shared__ unsigned short agh[16*PR];
  __shared__ unsigned short agl[16*PR];
  const int tid = threadIdx.x;
  const int lane = tid & 63;
  const int wv = tid >> 6;
  const int l15 = lane & 15;
  const int lg  = lane >> 4;
  // XCD-clustered remap (dispatch round-robin: bid&7 ~ XCD)
  const int bid = blockIdx.x;
  const int q = bid >> 3;
  const int hi2 = (q >= 250);
  const int inst = (bid & 7) + (hi2 ? 8 : 0);
  const int node0 = (hi2 ? q - 250 : q)*16;
  const size_t ibase = (size_t)inst*NN;
  // ---- Phase A: one node per 16-lane group; 2 edges per iteration (4 loads in flight) ----
  {
    const int nl = wv*4 + lg;
    const int node = node0 + nl;
    const int p0 = ptr[node], p1 = ptr[node+1];
    const float4 adv = *(const float4*)&ald[(ibase+node)*4];
    const float ad[4] = {adv.x, adv.y, adv.z, adv.w};
    float den[4] = {0.f,0.f,0.f,0.f};
    float a[4][VPL];
    #pragma unroll
    for (int h=0;h<4;h++)
      #pragma unroll
      for (int c=0;c<VPL;c++) a[h][c] = 0.f;
    auto ldx = [&](int s, float (&xv)[VPL]){
      if constexpr (VPL == 4){
        float4 x4 = *(const float4*)&xin[(ibase + s)*(size_t)KF + l15*4];
        xv[0]=x4.x; xv[1]=x4.y; xv[2]=x4.z; xv[3]=x4.w;
      } else {
        float2 x2 = *(const float2*)&xin[(ibase + s)*(size_t)KF + l15*2];
        xv[0]=x2.x; xv[1]=x2.y;
      }
    };
    int p = p0;
    for (; p + 2 <= p1; p += 2){
      const int s0 = srcs[p], s1 = srcs[p+1];
      const float4 av0 = *(const float4*)&als[(ibase + s0)*4];
      const float4 av1 = *(const float4*)&als[(ibase + s1)*4];
      float xv0[VPL], xv1[VPL];
      ldx(s0, xv0);
      ldx(s1, xv1);
      const float ac0[4] = {av0.x, av0.y, av0.z, av0.w};
      const float ac1[4] = {av1.x, av1.y, av1.z, av1.w};
      #pragma unroll
      for (int h=0;h<4;h++){
        float v0 = ac0[h] + ad[h];
        v0 = (v0 >= 0.f) ? v0 : 0.2f*v0;
        float e0 = fexp2(v0*1.44269504f);
        float v1 = ac1[h] + ad[h];
        v1 = (v1 >= 0.f) ? v1 : 0.2f*v1;
        float e1 = fexp2(v1*1.44269504f);
        den[h] += e0 + e1;
        #pragma unroll
        for (int c=0;c<VPL;c++)
          a[h][c] = fmaf(e0, xv0[c], fmaf(e1, xv1[c], a[h][c]));
      }
    }
    if (p < p1){                       // tail (odd degree)
      const int s0 = srcs[p];
      const float4 av0 = *(const float4*)&als[(ibase + s0)*4];
      float xv0[VPL];
      ldx(s0, xv0);
      const float ac0[4] = {av0.x, av0.y, av0.z, av0.w};
      #pragma unroll
      for (int h=0;h<4;h++){
        float v0 = ac0[h] + ad[h];
        v0 = (v0 >= 0.f) ? v0 : 0.2f*v0;
        float e0 = fexp2(v0*1.44269504f);
        den[h] += e0;
        #pragma unroll
        for (int c=0;c<VPL;c++) a[h][c] = fmaf(e0, xv0[c], a[h][c]);
      }
    }
    // epilogue per lane: normalize + trunc-split pack (hi exact mask, lo rne)
    #pragma unroll
    for (int h=0;h<4;h++){
      float inv = 0.25f * frcp(den[h]);
      unsigned short vh[VPL], vl[VPL];
      #pragma unroll
      for (int c=0;c<VPL;c++){
        float v = a[h][c]*inv;
        unsigned uh = __float_as_uint(v) & 0xFFFF0000u;
        vh[c] = (unsigned short)(uh >> 16);
        vl[c] = bf16rne(v - __uint_as_float(uh));
      }
      if constexpr (VPL == 4){
        uint2 ph = {((unsigned)vh[1]<<16)|vh[0], ((unsigned)vh[3]<<16)|vh[2]};
        uint2 pl = {((unsigned)vl[1]<<16)|vl[0], ((unsigned)vl[3]<<16)|vl[2]};
        *(uint2*)&agh[nl*PR + h*KF + l15*4] = ph;
        *(uint2*)&agl[nl*PR + h*KF + l15*4] = pl;
      } else {
        *(unsigned*)&agh[nl*PR + h*KF + l15*2] = ((unsigned)vh[1]<<16)|vh[0];
        *(unsigned*)&agl[nl*PR + h*KF + l15*2] = ((unsigned)vl[1]<<16)|vl[0];
      }
    }
  }
  __syncthreads();
  // ---- Phase B: out[16 nodes][64 cols] = aggs @ Wb via 3-term split MFMA ----
  f32x4 acc = {0.f,0.f,0.f,0.f};
  #pragma unroll
  for (int kc=0; kc<NKC; kc++){
    size_t fl = (size_t)((wv*NKC + kc)*64 + lane)*8;
    short8v BH = *(const short8v*)&wbh[fl];
    short8v BL = *(const short8v*)&wbl[fl];
    int aoff = l15*PR + kc*32 + lg*8;
    short8v AH = *(const short8v*)&agh[aoff];
    short8v AL = *(const short8v*)&agl[aoff];
    acc = __builtin_amdgcn_mfma_f32_16x16x32_bf16(AH, BH, acc, 0,0,0);
    acc = __builtin_amdgcn_mfma_f32_16x16x32_bf16(AH, BL, acc, 0,0,0);
    acc = __builtin_amdgcn_mfma_f32_16x16x32_bf16(AL, BH, acc, 0,0,0);
  }
  const int c = wv*16 + l15;
  const float bv = bias[c];
  #pragma unroll
  for (int r=0;r<4;r++){
    int node = node0 + lg*4 + r;
    float val = fmaxf(acc[r] + bv, 0.f);
    size_t oi = (ibase + node)*CC + c;
    if constexpr (SPLIT){
      unsigned short hv = bf16rne(val);
      ohi[oi] = hv;
      olo[oi] = bf16rne(val - bf2f(hv));
    } else {
      outp[oi] = val;
    }
  }
}

// ---------------- MFMA LSTM v10: 16 rows/block + cross-step weight/x prefetch (T14) -------------
__device__ __forceinline__ void mfma12(const short8v &AH, const short8v &AL,
                                       const short8v (&BH)[4], const short8v (&BL)[4],
                                       f32x4 (&acc)[4]){
  #pragma unroll
  for (int gg=0;gg<4;gg++)
    acc[gg] = __builtin_amdgcn_mfma_f32_16x16x32_bf16(AH, BH[gg], acc[gg], 0,0,0);
  #pragma unroll
  for (int gg=0;gg<4;gg++)
    acc[gg] = __builtin_amdgcn_mfma_f32_16x16x32_bf16(AH, BL[gg], acc[gg], 0,0,0);
  #pragma unroll
  for (int gg=0;gg<4;gg++)
    acc[gg] = __builtin_amdgcn_mfma_f32_16x16x32_bf16(AL, BH[gg], acc[gg], 0,0,0);
}

__global__ __launch_bounds__(512) void k_lstm10(
    const unsigned short* __restrict__ ghi, const unsigned short* __restrict__ glo,
    const unsigned short* __restrict__ wfh, const unsigned short* __restrict__ wfl,
    const float* __restrict__ bih, const float* __restrict__ bhh,
    const float* __restrict__ WfT, const float* __restrict__ bfv,
    const float* __restrict__ Wo, const float* __restrict__ bo,
    float* __restrict__ out){
  __shared__ unsigned short hhi[ROWSL*PADU];
  __shared__ unsigned short hlo[ROWSL*PADU];
  __shared__ float catf[ROWSL*PADC];   // cols 0..127 = h_final, 128..191 = g_last
  __shared__ float red[ROWSL*FHN];
  const int tid = threadIdx.x;
  const int lane = tid & 63;
  const int wv = tid >> 6;             // 0..7
  const int l15 = lane & 15;
  const int lg  = lane >> 4;           // 0..3
  const int r0 = blockIdx.x*ROWSL;
  const int b  = r0 / NN;
  const int n0 = r0 % NN;
  float bias[4];
  #pragma unroll
  for (int gg=0; gg<4; gg++){
    int n = gg*128 + wv*16 + l15;
    bias[gg] = bih[n] + bhh[n];
  }
  float c01[4];
  #pragma unroll
  for (int r=0;r<4;r++) c01[r]=0.f;
  auto ldw = [&](int kc, short8v (&BH)[4], short8v (&BL)[4]){
    #pragma unroll
    for (int gg=0;gg<4;gg++){
      size_t fl = (size_t)(((gg*8+wv)*6 + kc)*64 + lane)*8;
      BH[gg] = *(const short8v*)&wfh[fl];
      BL[gg] = *(const short8v*)&wfl[fl];
    }
  };
  auto ldax = [&](int t, short8v (&AH)[2], short8v (&AL)[2]){
    const size_t row = ((size_t)(b*TT+t)*NN + n0 + l15);
    #pragma unroll
    for (int kc=0; kc<2; kc++){
      size_t off = row*64 + kc*32 + lg*8;
      AH[kc] = *(const short8v*)&ghi[off];
      AL[kc] = *(const short8v*)&glo[off];
    }
  };
  auto ldh = [&](int kcr, short8v &AH, short8v &AL){
    int off = l15*PADU + kcr*32 + lg*8;
    AH = *(const short8v*)&hhi[off];
    AL = *(const short8v*)&hlo[off];
  };

  // preload: x-frags for t=0 and weight chunk 0
  short8v axH[2], axL[2];
  ldax(0, axH, axL);
  short8v BHa[4], BLa[4], BHb[4], BLb[4];
  ldw(0, BHa, BLa);

  for (int t=0;t<TT;t++){
    f32x4 acc[4];
    #pragma unroll
    for (int gg=0;gg<4;gg++){
      acc[gg][0]=bias[gg]; acc[gg][1]=bias[gg];
      acc[gg][2]=bias[gg]; acc[gg][3]=bias[gg];
    }
    ldw(1, BHb, BLb);
    // chunk 0 (x)
    mfma12(axH[0], axL[0], BHa, BLa, acc);
    short8v AH, AL;
    if (t > 0){
      ldw(2, BHa, BLa);
      // chunk 1 (x)
      mfma12(axH[1], axL[1], BHb, BLb, acc);
      // ax now dead: prefetch x-frags for t+1 (land during h-part + gates + barrier)
      if (t+1 < TT) ldax(t+1, axH, axL);
      ldw(3, BHb, BLb);
      ldh(0, AH, AL); mfma12(AH, AL, BHa, BLa, acc);   // chunk 2 (h)
      ldw(4, BHa, BLa);
      ldh(1, AH, AL); mfma12(AH, AL, BHb, BLb, acc);   // chunk 3 (h)
      ldw(5, BHb, BLb);
      ldh(2, AH, AL); mfma12(AH, AL, BHa, BLa, acc);   // chunk 4 (h)
      if (t+1 < TT) ldw(0, BHa, BLa);                  // prefetch next-step chunk 0
      ldh(3, AH, AL); mfma12(AH, AL, BHb, BLb, acc);   // chunk 5 (h)
    } else {
      // t=0: h=0, only x-part
      mfma12(axH[1], axL[1], BHb, BLb, acc);
      ldax(1, axH, axL);                               // prefetch x for t=1
      ldw(0, BHa, BLa);                                // prefetch chunk 0 for t=1
    }
    // gates (i,f,g,o), thread-local — covers prefetch latency
    unsigned short hh_[4], hl_[4];
    float hv_[4];
    #pragma unroll
    for (int r=0;r<4;r++){
      float zi = acc[0][r], zf = acc[1][r], zg = acc[2][r], zo = acc[3][r];
      float cv = fsig(zf)*c01[r] + fsig(zi)*ftanh(zg);
      c01[r] = cv;
      float hv = fsig(zo)*ftanh(cv);
      hv_[r] = hv;
      unsigned short hi = bf16rne(hv);
      hh_[r] = hi;
      hl_[r] = bf16rne(hv - bf2f(hi));
    }
    if (t > 0) __syncthreads();        // all reads of h(t) complete before overwrite
    if (t < TT-1){
      #pragma unroll
      for (int r=0;r<4;r++){
        int m = lg*4 + r;
        int u = wv*16 + l15;
        hhi[m*PADU + u] = hh_[r];
        hlo[m*PADU + u] = hl_[r];
      }
    } else {
      #pragma unroll
      for (int r=0;r<4;r++){
        int m = lg*4 + r;
        int u = wv*16 + l15;
        catf[m*PADC + u] = hv_[r];
      }
      // g_last reconstructed from bf16 hi/lo split (16 rows x 16 float4)
      if (tid < ROWSL*16){
        const size_t grow = ((size_t)(b*TT+TT-1)*NN + n0)*CC;
        int rr = tid >> 4, c4 = (tid & 15)*4;
        int idx = rr*CC + c4;
        #pragma unroll
        for (int qq=0;qq<4;qq++)
          catf[rr*PADC + 128 + c4 + qq] = bf2f(ghi[grow+idx+qq]) + bf2f(glo[grow+idx+qq]);
      }
    }
    __syncthreads();
  }
  // ---- fused output MLP from catf (16 rows, 4 per thread-group) ----
  const int u = tid & 127;
  const int rg = tid >> 7;             // 0..3
  float fa[4];
  #pragma unroll
  for (int r=0;r<4;r++) fa[r] = bfv[u];
  for (int k4=0;k4<48;k4++){
    float4 wf = *(const float4*)&WfT[u*192 + k4*4];
    #pragma unroll
    for (int r=0;r<4;r++){
      float4 cv = *(const float4*)&catf[(rg*4+r)*PADC + k4*4];
      fa[r] = fmaf(cv.x,wf.x,fmaf(cv.y,wf.y,fmaf(cv.z,wf.z,fmaf(cv.w,wf.w,fa[r]))));
    }
  }
  float wo = Wo[u];
  #pragma unroll
  for (int r=0;r<4;r++) fa[r] = fmaxf(fa[r], 0.f) * wo;
  #pragma unroll
  for (int r=0;r<4;r++) red[(rg*4+r)*FHN + u] = fa[r];
  __syncthreads();
  for (int s=64;s>=1;s>>=1){
    if (u < s){
      #pragma unroll
      for (int r=0;r<4;r++) red[(rg*4+r)*FHN + u] += red[(rg*4+r)*FHN + u + s];
    }
    __syncthreads();
  }
  if (u == 0){
    #pragma unroll
    for (int r=0;r<4;r++) out[r0 + rg*4 + r] = red[(rg*4+r)*FHN] + bo[0];
  }
}

// ---------------- launch ----------------
extern "C" void kernel_launch(void* const* d_in, const int* in_sizes, int n_in,
                              void* d_out, int out_size, void* d_ws, size_t ws_size,
                              hipStream_t stream) {
  const float* x_seq  = (const float*)d_in[0];
  const float* W1     = (const float*)d_in[1];
  const float* a_src1 = (const float*)d_in[2];
  const float* a_dst1 = (const float*)d_in[3];
  const float* b1     = (const float*)d_in[4];
  const float* W2     = (const float*)d_in[5];
  const float* a_src2 = (const float*)d_in[6];
  const float* a_dst2 = (const float*)d_in[7];
  const float* b2     = (const float*)d_in[8];
  const float* W_ih   = (const float*)d_in[9];
  const float* W_hh   = (const float*)d_in[10];
  const float* b_ih   = (const float*)d_in[11];
  const float* b_hh   = (const float*)d_in[12];
  const float* Wf     = (const float*)d_in[13];
  const float* bfv    = (const float*)d_in[14];
  const float* Wo     = (const float*)d_in[15];
  const float* bo     = (const float*)d_in[16];
  const int*   ei     = (const int*)d_in[17];
  const int* e_src = ei;
  const int* e_dst = ei + EE;
  float* out = (float*)d_out;

  char* w = (char*)d_ws;
  auto alloc = [&](size_t bytes)->char*{
    char* p = w; w += (bytes + 255) & ~(size_t)255; return p;
  };
  float* als   = (float*)alloc((size_t)BT*NN*HH*4);
  float* ald   = (float*)alloc((size_t)BT*NN*HH*4);
  float* gat1  = (float*)alloc((size_t)BT*NN*CC*4);                 // layer1 out fp32
  unsigned short* ghi = (unsigned short*)alloc((size_t)BT*NN*CC*2); // layer2 out bf16-hi
  unsigned short* glo = (unsigned short*)alloc((size_t)BT*NN*CC*2); // layer2 out bf16-lo
  unsigned short* wfh = (unsigned short*)alloc((size_t)12288*8*2);  // LSTM W frag hi
  unsigned short* wfl = (unsigned short*)alloc((size_t)12288*8*2);  // LSTM W frag lo
  unsigned short* wb1h = (unsigned short*)alloc((size_t)1024*8*2);  // GAT1 Wb frag hi
  unsigned short* wb1l = (unsigned short*)alloc((size_t)1024*8*2);
  unsigned short* wb2h = (unsigned short*)alloc((size_t)2048*8*2);  // GAT2 Wb frag hi
  unsigned short* wb2l = (unsigned short*)alloc((size_t)2048*8*2);
  float* WfT   = (float*)alloc((size_t)128*192*4);
  float* wt    = (float*)alloc((size_t)768*4);
  int* cnt     = (int*)alloc((size_t)2*NN*4);
  int* cur     = cnt + NN;
  int* ptr     = (int*)alloc((size_t)(NN+1)*4);
  int* idxa    = (int*)alloc((size_t)NE*4);
  int* srcs    = (int*)alloc((size_t)NE*4);

  // merged prep
  k_prep<<<(2*NN+768+12288+24576+1024+2048+255)/256, 256, 0, stream>>>(
      cnt, W1, a_src1, a_dst1, W2, a_src2, a_dst2, wt, W_ih, W_hh, wfh, wfl, Wf, WfT,
      wb1h, wb1l, wb2h, wb2l);
  // CSR build (same graph for all 16 instances)
  k_count<<<(NE+255)/256, 256, 0, stream>>>(e_dst, cnt);
  k_scan<<<1, 1024, 0, stream>>>(cnt, ptr);
  k_scatter<<<(NE+255)/256, 256, 0, stream>>>(e_dst, ptr, cur, idxa);
  k_sortseg<<<(NN+255)/256, 256, 0, stream>>>(ptr, idxa, e_src, srcs);

  // GAT layer 1 (32-dim x-space agg, 2-edge unrolled gather)
  k_coef3<32><<<(BT*NN+255)/256, 256, 0, stream>>>(x_seq, wt, wt+128, als, ald);
  k_gatt<32,false><<<4000, 256, 0, stream>>>(ptr, srcs, als, ald, x_seq, wb1h, wb1l, b1,
                                             gat1, nullptr, nullptr);
  // GAT layer 2 (64-dim) — emits bf16-split g only
  k_coef3<64><<<(BT*NN+255)/256, 256, 0, stream>>>(gat1, wt+256, wt+512, als, ald);
  k_gatt<64,true><<<4000, 256, 0, stream>>>(ptr, srcs, als, ald, gat1, wb2h, wb2l, b2,
                                            nullptr, ghi, glo);

  // MFMA LSTM + fused output MLP (cross-step prefetch)
  k_lstm10<<<BB*NN/ROWSL, 512, 0, stream>>>(ghi, glo, wfh, wfl, b_ih, b_hh, WfT, bfv, Wo, bo, out);
}

// Round 18
// 223.952 us; speedup vs baseline: 1.1602x; 1.1602x over previous
//
#include <hip/hip_runtime.h>
#include <math.h>

#define NN 4000
#define EE 40000
#define NE 44000   // EE + NN self-loops
#define BB 2
#define TT 8
#define BT 16      // B*T graph instances
#define HH 4
#define CC 64
#define HC 256     // H*C
#define HLN 128    // lstm hidden
#define G4 512     // 4*HLN
#define FHN 128
#define ROWSL 16   // lstm rows per block
#define PADU 136   // ushort pad for h LDS rows
#define PADC 196   // fp32 pad for cat LDS rows

typedef __attribute__((ext_vector_type(8))) short short8v;
typedef __attribute__((ext_vector_type(4))) float f32x4;

__device__ __forceinline__ float fexp2(float x){ return __builtin_amdgcn_exp2f(x); }
__device__ __forceinline__ float frcp(float x){ return __builtin_amdgcn_rcpf(x); }
__device__ __forceinline__ float fsig(float x){ return frcp(1.f + fexp2(x * -1.44269504f)); }
__device__ __forceinline__ float ftanh(float x){
  float xx = fminf(fmaxf(x, -10.f), 10.f);
  float e = fexp2(xx * 2.88539008f);
  return (e - 1.f) * frcp(e + 1.f);
}
__device__ __forceinline__ unsigned short bf16rne(float x){
  unsigned u = __float_as_uint(x);
  return (unsigned short)((u + 0x7FFFu + ((u>>16)&1u)) >> 16);
}
__device__ __forceinline__ float bf2f(unsigned short h){ return __uint_as_float(((unsigned)h)<<16); }

// ---------------- CSR build (deterministic: atomic scatter + per-segment sort) ----------------
__global__ void k_count(const int* __restrict__ dst, int* __restrict__ cnt){
  int e = blockIdx.x*256+threadIdx.x;
  if (e >= NE) return;
  int d = (e < EE) ? dst[e] : (e - EE);
  atomicAdd(&cnt[d], 1);
}

__global__ __launch_bounds__(1024) void k_scan(const int* __restrict__ cnt, int* __restrict__ ptr){
  __shared__ int part[1024];
  const int n = NN;
  int t = threadIdx.x;
  int base = t*4;
  int loc[4]; int s = 0;
  #pragma unroll
  for (int i=0;i<4;i++){ int c = (base+i < n) ? cnt[base+i] : 0; loc[i] = s; s += c; }
  part[t] = s;
  __syncthreads();
  for (int off=1; off<1024; off<<=1){
    int add = (t >= off) ? part[t-off] : 0;
    __syncthreads();
    part[t] += add;
    __syncthreads();
  }
  int ebase = (t > 0) ? part[t-1] : 0;
  #pragma unroll
  for (int i=0;i<4;i++){ if (base+i < n) ptr[base+i] = ebase + loc[i]; }
  if (t == 1023) ptr[n] = part[1023];
}

__global__ void k_scatter(const int* __restrict__ dst, const int* __restrict__ ptr,
                          int* __restrict__ cur, int* __restrict__ idxa){
  int e = blockIdx.x*256+threadIdx.x;
  if (e >= NE) return;
  int d = (e < EE) ? dst[e] : (e - EE);
  int pos = atomicAdd(&cur[d], 1);
  idxa[ptr[d]+pos] = e;
}

// sort each segment (deterministic order) and emit position-indexed src
__global__ void k_sortseg(const int* __restrict__ ptr, int* __restrict__ idxa,
                          const int* __restrict__ e0, int* __restrict__ srcs){
  int node = blockIdx.x*256+threadIdx.x;
  if (node >= NN) return;
  int p0 = ptr[node], p1 = ptr[node+1];
  for (int i=p0+1;i<p1;i++){
    int key = idxa[i]; int j = i-1;
    while (j >= p0 && idxa[j] > key){ idxa[j+1] = idxa[j]; j--; }
    idxa[j+1] = key;
  }
  for (int p=p0;p<p1;p++){
    int e = idxa[p];
    srcs[p] = (e < EE) ? e0[e] : (e - EE);
  }
}

// ------- merged prep: zero cnt | wtilde | LSTM frags | WfT | GAT Wb frags (bf16 hi/lo) ----------
__global__ void k_prep(int* __restrict__ cnt,
                       const float* __restrict__ W1, const float* __restrict__ as1, const float* __restrict__ ad1,
                       const float* __restrict__ W2, const float* __restrict__ as2, const float* __restrict__ ad2,
                       float* __restrict__ wt,
                       const float* __restrict__ Wih, const float* __restrict__ Whh,
                       unsigned short* __restrict__ wfh, unsigned short* __restrict__ wfl,
                       const float* __restrict__ Wf, float* __restrict__ WfT,
                       unsigned short* __restrict__ wb1h, unsigned short* __restrict__ wb1l,
                       unsigned short* __restrict__ wb2h, unsigned short* __restrict__ wb2l){
  int i = blockIdx.x*256 + threadIdx.x;
  if (i < 2*NN){ cnt[i] = 0; return; }
  i -= 2*NN;
  if (i < 768){
    if (i < 256){                      // layer1 wtilde: sd*128 + h*32 + k
      int sd = i >> 7, h = (i >> 5) & 3, k = i & 31;
      const float* a = sd ? ad1 : as1;
      float s = 0.f;
      for (int c=0;c<CC;c++) s = fmaf(W1[k*HC + h*CC + c], a[h*CC + c], s);
      wt[sd*128 + h*32 + k] = s;
    } else {
      int j = i - 256;
      int sd = j >> 8, h = (j >> 6) & 3, k = j & 63;
      const float* a = sd ? ad2 : as2;
      float s = 0.f;
      for (int c=0;c<CC;c++) s = fmaf(W2[k*HC + h*CC + c], a[h*CC + c], s);
      wt[256 + sd*256 + h*64 + k] = s;
    }
    return;
  }
  i -= 768;
  if (i < 12288){                      // LSTM B-fragments (bf16 hi/lo split)
    int lane = i & 63;
    int kc = (i >> 6) % 6;
    int wk = i / (64*6);
    int w = wk & 7, gg = wk >> 3;
    int n = gg*128 + w*16 + (lane & 15);
    int kbase = kc*32 + (lane >> 4)*8;
    #pragma unroll
    for (int j=0;j<8;j++){
      int k = kbase + j;
      float v = (k < 64) ? Wih[n*64 + k] : Whh[n*128 + (k-64)];
      unsigned short hi = bf16rne(v);
      wfh[(size_t)i*8 + j] = hi;
      wfl[(size_t)i*8 + j] = bf16rne(v - bf2f(hi));
    }
    return;
  }
  i -= 12288;
  if (i < 24576){                      // WfT[u][k] = Wf[k][u]
    int u = i & 127, k = i >> 7;
    WfT[u*192 + k] = Wf[k*128 + u];
    return;
  }
  i -= 24576;
  if (i < 1024){                       // layer1 Wb frags: (nt*4 + kc)*64 + lane, KF=32
    int lane = i & 63, kc = (i >> 6) & 3, nt = i >> 8;
    int n = nt*16 + (lane & 15);
    int kb = kc*32 + (lane >> 4)*8;
    #pragma unroll
    for (int j=0;j<8;j++){
      int k = kb + j; int h = k >> 5; int kk = k & 31;
      float v = W1[kk*HC + h*CC + n];
      unsigned short hi = bf16rne(v);
      wb1h[(size_t)i*8 + j] = hi;
      wb1l[(size_t)i*8 + j] = bf16rne(v - bf2f(hi));
    }
    return;
  }
  i -= 1024;
  if (i < 2048){                       // layer2 Wb frags: (nt*8 + kc)*64 + lane, KF=64
    int lane = i & 63, kc = (i >> 6) & 7, nt = i >> 9;
    int n = nt*16 + (lane & 15);
    int kb = kc*32 + (lane >> 4)*8;
    #pragma unroll
    for (int j=0;j<8;j++){
      int k = kb + j; int h = k >> 6; int kk = k & 63;
      float v = W2[kk*HC + h*CC + n];
      unsigned short hi = bf16rne(v);
      wb2h[(size_t)i*8 + j] = hi;
      wb2l[(size_t)i*8 + j] = bf16rne(v - bf2f(hi));
    }
  }
}

// ---------------- attention coefficients: one thread per (inst,node), all 4 heads ----------------
template<int K>
__global__ void k_coef3(const float* __restrict__ x, const float* __restrict__ wts,
                        const float* __restrict__ wtd,
                        float* __restrict__ als, float* __restrict__ ald){
  int i = blockIdx.x*256+threadIdx.x;          // inst*NN + n
  if (i >= BT*NN) return;
  const float* xp = x + (size_t)i*K;
  float s1[4] = {0.f,0.f,0.f,0.f};
  float s2[4] = {0.f,0.f,0.f,0.f};
  for (int k=0;k<K;k+=4){
    float4 xv = *(const float4*)&xp[k];
    #pragma unroll
    for (int h=0;h<4;h++){
      float4 sv = *(const float4*)&wts[h*K+k];
      float4 dv = *(const float4*)&wtd[h*K+k];
      s1[h] = fmaf(xv.x,sv.x,fmaf(xv.y,sv.y,fmaf(xv.z,sv.z,fmaf(xv.w,sv.w,s1[h]))));
      s2[h] = fmaf(xv.x,dv.x,fmaf(xv.y,dv.y,fmaf(xv.z,dv.z,fmaf(xv.w,dv.w,s2[h]))));
    }
  }
  *(float4*)&als[(size_t)i*4] = make_float4(s1[0],s1[1],s1[2],s1[3]);
  *(float4*)&ald[(size_t)i*4] = make_float4(s2[0],s2[1],s2[2],s2[3]);
}

// ---- fused GAT layer v6: 16-lane group per node, 2-edge unrolled gather loop, MFMA GEMM ---------
template<int KF, bool SPLIT>
__global__ __launch_bounds__(256) void k_gatt(const int* __restrict__ ptr, const int* __restrict__ srcs,
    const float* __restrict__ als, const float* __restrict__ ald, const float* __restrict__ xin,
    const unsigned short* __restrict__ wbh, const unsigned short* __restrict__ wbl,
    const float* __restrict__ bias, float* __restrict__ outp,
    unsigned short* __restrict__ ohi, unsigned short* __restrict__ olo){
  constexpr int K = HH*KF;            // 128 / 256
  constexpr int PR = K + 8;           // padded row in ushorts
  constexpr int NKC = K/32;           // 4 / 8
  constexpr int VPL = KF/16;          // floats per lane: 2 (KF=32) or 4 (KF=64)
  __shared__ unsigned short agh[16*PR];
  __shared__ unsigned short agl[16*PR];
  const int tid = threadIdx.x;
  const int lane = tid & 63;
  const int wv = tid >> 6;
  const int l15 = lane & 15;
  const int lg  = lane >> 4;
  // XCD-clustered remap (dispatch round-robin: bid&7 ~ XCD)
  const int bid = blockIdx.x;
  const int q = bid >> 3;
  const int hi2 = (q >= 250);
  const int inst = (bid & 7) + (hi2 ? 8 : 0);
  const int node0 = (hi2 ? q - 250 : q)*16;
  const size_t ibase = (size_t)inst*NN;
  // ---- Phase A: one node per 16-lane group; 2 edges per iteration (4 loads in flight) ----
  {
    const int nl = wv*4 + lg;
    const int node = node0 + nl;
    const int p0 = ptr[node], p1 = ptr[node+1];
    const float4 adv = *(const float4*)&ald[(ibase+node)*4];
    const float ad[4] = {adv.x, adv.y, adv.z, adv.w};
    float den[4] = {0.f,0.f,0.f,0.f};
    float a[4][VPL];
    #pragma unroll
    for (int h=0;h<4;h++)
      #pragma unroll
      for (int c=0;c<VPL;c++) a[h][c] = 0.f;
    auto ldx = [&](int s, float (&xv)[VPL]){
      if constexpr (VPL == 4){
        float4 x4 = *(const float4*)&xin[(ibase + s)*(size_t)KF + l15*4];
        xv[0]=x4.x; xv[1]=x4.y; xv[2]=x4.z; xv[3]=x4.w;
      } else {
        float2 x2 = *(const float2*)&xin[(ibase + s)*(size_t)KF + l15*2];
        xv[0]=x2.x; xv[1]=x2.y;
      }
    };
    int p = p0;
    for (; p + 2 <= p1; p += 2){
      const int s0 = srcs[p], s1 = srcs[p+1];
      const float4 av0 = *(const float4*)&als[(ibase + s0)*4];
      const float4 av1 = *(const float4*)&als[(ibase + s1)*4];
      float xv0[VPL], xv1[VPL];
      ldx(s0, xv0);
      ldx(s1, xv1);
      const float ac0[4] = {av0.x, av0.y, av0.z, av0.w};
      const float ac1[4] = {av1.x, av1.y, av1.z, av1.w};
      #pragma unroll
      for (int h=0;h<4;h++){
        float v0 = ac0[h] + ad[h];
        v0 = (v0 >= 0.f) ? v0 : 0.2f*v0;
        float e0 = fexp2(v0*1.44269504f);
        float v1 = ac1[h] + ad[h];
        v1 = (v1 >= 0.f) ? v1 : 0.2f*v1;
        float e1 = fexp2(v1*1.44269504f);
        den[h] += e0 + e1;
        #pragma unroll
        for (int c=0;c<VPL;c++)
          a[h][c] = fmaf(e0, xv0[c], fmaf(e1, xv1[c], a[h][c]));
      }
    }
    if (p < p1){                       // tail (odd degree)
      const int s0 = srcs[p];
      const float4 av0 = *(const float4*)&als[(ibase + s0)*4];
      float xv0[VPL];
      ldx(s0, xv0);
      const float ac0[4] = {av0.x, av0.y, av0.z, av0.w};
      #pragma unroll
      for (int h=0;h<4;h++){
        float v0 = ac0[h] + ad[h];
        v0 = (v0 >= 0.f) ? v0 : 0.2f*v0;
        float e0 = fexp2(v0*1.44269504f);
        den[h] += e0;
        #pragma unroll
        for (int c=0;c<VPL;c++) a[h][c] = fmaf(e0, xv0[c], a[h][c]);
      }
    }
    // epilogue per lane: normalize + trunc-split pack (hi exact mask, lo rne)
    #pragma unroll
    for (int h=0;h<4;h++){
      float inv = 0.25f * frcp(den[h]);
      unsigned short vh[VPL], vl[VPL];
      #pragma unroll
      for (int c=0;c<VPL;c++){
        float v = a[h][c]*inv;
        unsigned uh = __float_as_uint(v) & 0xFFFF0000u;
        vh[c] = (unsigned short)(uh >> 16);
        vl[c] = bf16rne(v - __uint_as_float(uh));
      }
      if constexpr (VPL == 4){
        uint2 ph = {((unsigned)vh[1]<<16)|vh[0], ((unsigned)vh[3]<<16)|vh[2]};
        uint2 pl = {((unsigned)vl[1]<<16)|vl[0], ((unsigned)vl[3]<<16)|vl[2]};
        *(uint2*)&agh[nl*PR + h*KF + l15*4] = ph;
        *(uint2*)&agl[nl*PR + h*KF + l15*4] = pl;
      } else {
        *(unsigned*)&agh[nl*PR + h*KF + l15*2] = ((unsigned)vh[1]<<16)|vh[0];
        *(unsigned*)&agl[nl*PR + h*KF + l15*2] = ((unsigned)vl[1]<<16)|vl[0];
      }
    }
  }
  __syncthreads();
  // ---- Phase B: out[16 nodes][64 cols] = aggs @ Wb via 3-term split MFMA ----
  f32x4 acc = {0.f,0.f,0.f,0.f};
  #pragma unroll
  for (int kc=0; kc<NKC; kc++){
    size_t fl = (size_t)((wv*NKC + kc)*64 + lane)*8;
    short8v BH = *(const short8v*)&wbh[fl];
    short8v BL = *(const short8v*)&wbl[fl];
    int aoff = l15*PR + kc*32 + lg*8;
    short8v AH = *(const short8v*)&agh[aoff];
    short8v AL = *(const short8v*)&agl[aoff];
    acc = __builtin_amdgcn_mfma_f32_16x16x32_bf16(AH, BH, acc, 0,0,0);
    acc = __builtin_amdgcn_mfma_f32_16x16x32_bf16(AH, BL, acc, 0,0,0);
    acc = __builtin_amdgcn_mfma_f32_16x16x32_bf16(AL, BH, acc, 0,0,0);
  }
  const int c = wv*16 + l15;
  const float bv = bias[c];
  #pragma unroll
  for (int r=0;r<4;r++){
    int node = node0 + lg*4 + r;
    float val = fmaxf(acc[r] + bv, 0.f);
    size_t oi = (ibase + node)*CC + c;
    if constexpr (SPLIT){
      unsigned short hv = bf16rne(val);
      ohi[oi] = hv;
      olo[oi] = bf16rne(val - bf2f(hv));
    } else {
      outp[oi] = val;
    }
  }
}

// ---------------- MFMA LSTM v9 (proven r16): 16 rows/block, streamed weights, no prefetch -------
__device__ __forceinline__ void mfma12(const short8v &AH, const short8v &AL,
                                       const short8v (&BH)[4], const short8v (&BL)[4],
                                       f32x4 (&acc)[4]){
  #pragma unroll
  for (int gg=0;gg<4;gg++)
    acc[gg] = __builtin_amdgcn_mfma_f32_16x16x32_bf16(AH, BH[gg], acc[gg], 0,0,0);
  #pragma unroll
  for (int gg=0;gg<4;gg++)
    acc[gg] = __builtin_amdgcn_mfma_f32_16x16x32_bf16(AH, BL[gg], acc[gg], 0,0,0);
  #pragma unroll
  for (int gg=0;gg<4;gg++)
    acc[gg] = __builtin_amdgcn_mfma_f32_16x16x32_bf16(AL, BH[gg], acc[gg], 0,0,0);
}

__global__ __launch_bounds__(512) void k_lstm9(
    const unsigned short* __restrict__ ghi, const unsigned short* __restrict__ glo,
    const unsigned short* __restrict__ wfh, const unsigned short* __restrict__ wfl,
    const float* __restrict__ bih, const float* __restrict__ bhh,
    const float* __restrict__ WfT, const float* __restrict__ bfv,
    const float* __restrict__ Wo, const float* __restrict__ bo,
    float* __restrict__ out){
  __shared__ unsigned short hhi[ROWSL*PADU];
  __shared__ unsigned short hlo[ROWSL*PADU];
  __shared__ float catf[ROWSL*PADC];   // cols 0..127 = h_final, 128..191 = g_last
  __shared__ float red[ROWSL*FHN];
  const int tid = threadIdx.x;
  const int lane = tid & 63;
  const int wv = tid >> 6;             // 0..7
  const int l15 = lane & 15;
  const int lg  = lane >> 4;           // 0..3
  const int r0 = blockIdx.x*ROWSL;
  const int b  = r0 / NN;
  const int n0 = r0 % NN;
  float bias[4];
  #pragma unroll
  for (int gg=0; gg<4; gg++){
    int n = gg*128 + wv*16 + l15;
    bias[gg] = bih[n] + bhh[n];
  }
  float c01[4];
  #pragma unroll
  for (int r=0;r<4;r++) c01[r]=0.f;
  auto ldw = [&](int kc, short8v (&BH)[4], short8v (&BL)[4]){
    #pragma unroll
    for (int gg=0;gg<4;gg++){
      size_t fl = (size_t)(((gg*8+wv)*6 + kc)*64 + lane)*8;
      BH[gg] = *(const short8v*)&wfh[fl];
      BL[gg] = *(const short8v*)&wfl[fl];
    }
  };

  for (int t=0;t<TT;t++){
    short8v axH[2], axL[2];
    {
      const size_t row = ((size_t)(b*TT+t)*NN + n0 + l15);
      #pragma unroll
      for (int kc=0; kc<2; kc++){
        size_t off = row*64 + kc*32 + lg*8;
        axH[kc] = *(const short8v*)&ghi[off];
        axL[kc] = *(const short8v*)&glo[off];
      }
    }
    auto lda = [&](int kc, short8v &AH, short8v &AL){
      if (kc < 2){ AH = axH[kc]; AL = axL[kc]; }
      else {
        int off = l15*PADU + (kc-2)*32 + lg*8;
        AH = *(const short8v*)&hhi[off];
        AL = *(const short8v*)&hlo[off];
      }
    };
    f32x4 acc[4];
    #pragma unroll
    for (int gg=0;gg<4;gg++){
      acc[gg][0]=bias[gg]; acc[gg][1]=bias[gg];
      acc[gg][2]=bias[gg]; acc[gg][3]=bias[gg];
    }
    short8v BHa[4], BLa[4], BHb[4], BLb[4], AH, AL;
    if (t == 0){
      ldw(0, BHa, BLa);
      ldw(1, BHb, BLb);
      lda(0, AH, AL); mfma12(AH, AL, BHa, BLa, acc);
      lda(1, AH, AL); mfma12(AH, AL, BHb, BLb, acc);
    } else {
      ldw(0, BHa, BLa);
      ldw(1, BHb, BLb);
      lda(0, AH, AL); mfma12(AH, AL, BHa, BLa, acc);
      ldw(2, BHa, BLa);
      lda(1, AH, AL); mfma12(AH, AL, BHb, BLb, acc);
      ldw(3, BHb, BLb);
      lda(2, AH, AL); mfma12(AH, AL, BHa, BLa, acc);
      ldw(4, BHa, BLa);
      lda(3, AH, AL); mfma12(AH, AL, BHb, BLb, acc);
      ldw(5, BHb, BLb);
      lda(4, AH, AL); mfma12(AH, AL, BHa, BLa, acc);
      lda(5, AH, AL); mfma12(AH, AL, BHb, BLb, acc);
    }
    unsigned short hh_[4], hl_[4];
    float hv_[4];
    #pragma unroll
    for (int r=0;r<4;r++){
      float zi = acc[0][r], zf = acc[1][r], zg = acc[2][r], zo = acc[3][r];
      float cv = fsig(zf)*c01[r] + fsig(zi)*ftanh(zg);
      c01[r] = cv;
      float hv = fsig(zo)*ftanh(cv);
      hv_[r] = hv;
      unsigned short hi = bf16rne(hv);
      hh_[r] = hi;
      hl_[r] = bf16rne(hv - bf2f(hi));
    }
    if (t > 0) __syncthreads();        // all reads of h(t) complete before overwrite
    if (t < TT-1){
      #pragma unroll
      for (int r=0;r<4;r++){
        int m = lg*4 + r;
        int u = wv*16 + l15;
        hhi[m*PADU + u] = hh_[r];
        hlo[m*PADU + u] = hl_[r];
      }
    } else {
      #pragma unroll
      for (int r=0;r<4;r++){
        int m = lg*4 + r;
        int u = wv*16 + l15;
        catf[m*PADC + u] = hv_[r];
      }
      // g_last reconstructed from bf16 hi/lo split (16 rows x 16 float4)
      if (tid < ROWSL*16){
        const size_t grow = ((size_t)(b*TT+TT-1)*NN + n0)*CC;
        int rr = tid >> 4, c4 = (tid & 15)*4;
        int idx = rr*CC + c4;
        #pragma unroll
        for (int qq=0;qq<4;qq++)
          catf[rr*PADC + 128 + c4 + qq] = bf2f(ghi[grow+idx+qq]) + bf2f(glo[grow+idx+qq]);
      }
    }
    __syncthreads();
  }
  // ---- fused output MLP from catf (16 rows, 4 per thread-group) ----
  const int u = tid & 127;
  const int rg = tid >> 7;             // 0..3
  float fa[4];
  #pragma unroll
  for (int r=0;r<4;r++) fa[r] = bfv[u];
  for (int k4=0;k4<48;k4++){
    float4 wf = *(const float4*)&WfT[u*192 + k4*4];
    #pragma unroll
    for (int r=0;r<4;r++){
      float4 cv = *(const float4*)&catf[(rg*4+r)*PADC + k4*4];
      fa[r] = fmaf(cv.x,wf.x,fmaf(cv.y,wf.y,fmaf(cv.z,wf.z,fmaf(cv.w,wf.w,fa[r]))));
    }
  }
  float wo = Wo[u];
  #pragma unroll
  for (int r=0;r<4;r++) fa[r] = fmaxf(fa[r], 0.f) * wo;
  #pragma unroll
  for (int r=0;r<4;r++) red[(rg*4+r)*FHN + u] = fa[r];
  __syncthreads();
  for (int s=64;s>=1;s>>=1){
    if (u < s){
      #pragma unroll
      for (int r=0;r<4;r++) red[(rg*4+r)*FHN + u] += red[(rg*4+r)*FHN + u + s];
    }
    __syncthreads();
  }
  if (u == 0){
    #pragma unroll
    for (int r=0;r<4;r++) out[r0 + rg*4 + r] = red[(rg*4+r)*FHN] + bo[0];
  }
}

// ---------------- launch ----------------
extern "C" void kernel_launch(void* const* d_in, const int* in_sizes, int n_in,
                              void* d_out, int out_size, void* d_ws, size_t ws_size,
                              hipStream_t stream) {
  const float* x_seq  = (const float*)d_in[0];
  const float* W1     = (const float*)d_in[1];
  const float* a_src1 = (const float*)d_in[2];
  const float* a_dst1 = (const float*)d_in[3];
  const float* b1     = (const float*)d_in[4];
  const float* W2     = (const float*)d_in[5];
  const float* a_src2 = (const float*)d_in[6];
  const float* a_dst2 = (const float*)d_in[7];
  const float* b2     = (const float*)d_in[8];
  const float* W_ih   = (const float*)d_in[9];
  const float* W_hh   = (const float*)d_in[10];
  const float* b_ih   = (const float*)d_in[11];
  const float* b_hh   = (const float*)d_in[12];
  const float* Wf     = (const float*)d_in[13];
  const float* bfv    = (const float*)d_in[14];
  const float* Wo     = (const float*)d_in[15];
  const float* bo     = (const float*)d_in[16];
  const int*   ei     = (const int*)d_in[17];
  const int* e_src = ei;
  const int* e_dst = ei + EE;
  float* out = (float*)d_out;

  char* w = (char*)d_ws;
  auto alloc = [&](size_t bytes)->char*{
    char* p = w; w += (bytes + 255) & ~(size_t)255; return p;
  };
  float* als   = (float*)alloc((size_t)BT*NN*HH*4);
  float* ald   = (float*)alloc((size_t)BT*NN*HH*4);
  float* gat1  = (float*)alloc((size_t)BT*NN*CC*4);                 // layer1 out fp32
  unsigned short* ghi = (unsigned short*)alloc((size_t)BT*NN*CC*2); // layer2 out bf16-hi
  unsigned short* glo = (unsigned short*)alloc((size_t)BT*NN*CC*2); // layer2 out bf16-lo
  unsigned short* wfh = (unsigned short*)alloc((size_t)12288*8*2);  // LSTM W frag hi
  unsigned short* wfl = (unsigned short*)alloc((size_t)12288*8*2);  // LSTM W frag lo
  unsigned short* wb1h = (unsigned short*)alloc((size_t)1024*8*2);  // GAT1 Wb frag hi
  unsigned short* wb1l = (unsigned short*)alloc((size_t)1024*8*2);
  unsigned short* wb2h = (unsigned short*)alloc((size_t)2048*8*2);  // GAT2 Wb frag hi
  unsigned short* wb2l = (unsigned short*)alloc((size_t)2048*8*2);
  float* WfT   = (float*)alloc((size_t)128*192*4);
  float* wt    = (float*)alloc((size_t)768*4);
  int* cnt     = (int*)alloc((size_t)2*NN*4);
  int* cur     = cnt + NN;
  int* ptr     = (int*)alloc((size_t)(NN+1)*4);
  int* idxa    = (int*)alloc((size_t)NE*4);
  int* srcs    = (int*)alloc((size_t)NE*4);

  // merged prep
  k_prep<<<(2*NN+768+12288+24576+1024+2048+255)/256, 256, 0, stream>>>(
      cnt, W1, a_src1, a_dst1, W2, a_src2, a_dst2, wt, W_ih, W_hh, wfh, wfl, Wf, WfT,
      wb1h, wb1l, wb2h, wb2l);
  // CSR build (same graph for all 16 instances)
  k_count<<<(NE+255)/256, 256, 0, stream>>>(e_dst, cnt);
  k_scan<<<1, 1024, 0, stream>>>(cnt, ptr);
  k_scatter<<<(NE+255)/256, 256, 0, stream>>>(e_dst, ptr, cur, idxa);
  k_sortseg<<<(NN+255)/256, 256, 0, stream>>>(ptr, idxa, e_src, srcs);

  // GAT layer 1 (32-dim x-space agg, 2-edge unrolled gather)
  k_coef3<32><<<(BT*NN+255)/256, 256, 0, stream>>>(x_seq, wt, wt+128, als, ald);
  k_gatt<32,false><<<4000, 256, 0, stream>>>(ptr, srcs, als, ald, x_seq, wb1h, wb1l, b1,
                                             gat1, nullptr, nullptr);
  // GAT layer 2 (64-dim) — emits bf16-split g only
  k_coef3<64><<<(BT*NN+255)/256, 256, 0, stream>>>(gat1, wt+256, wt+512, als, ald);
  k_gatt<64,true><<<4000, 256, 0, stream>>>(ptr, srcs, als, ald, gat1, wb2h, wb2l, b2,
                                            nullptr, ghi, glo);

  // MFMA LSTM + fused output MLP (proven spill-free v9)
  k_lstm9<<<BB*NN/ROWSL, 512, 0, stream>>>(ghi, glo, wfh, wfl, b_ih, b_hh, WfT, bfv, Wo, bo, out);
}

// Round 19
// 211.833 us; speedup vs baseline: 1.2266x; 1.0572x over previous
//
#include <hip/hip_runtime.h>
#include <math.h>

#define NN 4000
#define EE 40000
#define NE 44000   // EE + NN self-loops
#define BB 2
#define TT 8
#define BT 16      // B*T graph instances
#define HH 4
#define CC 64
#define HC 256     // H*C
#define HLN 128    // lstm hidden
#define G4 512     // 4*HLN
#define FHN 128
#define PADU 136   // ushort pad for h LDS rows
#define PADC 196   // fp32 pad for cat LDS rows

typedef __attribute__((ext_vector_type(8))) short short8v;
typedef __attribute__((ext_vector_type(4))) float f32x4;

__device__ __forceinline__ float fexp2(float x){ return __builtin_amdgcn_exp2f(x); }
__device__ __forceinline__ float frcp(float x){ return __builtin_amdgcn_rcpf(x); }
__device__ __forceinline__ float fsig(float x){ return frcp(1.f + fexp2(x * -1.44269504f)); }
__device__ __forceinline__ float ftanh(float x){
  float xx = fminf(fmaxf(x, -10.f), 10.f);
  float e = fexp2(xx * 2.88539008f);
  return (e - 1.f) * frcp(e + 1.f);
}
__device__ __forceinline__ unsigned short bf16rne(float x){
  unsigned u = __float_as_uint(x);
  return (unsigned short)((u + 0x7FFFu + ((u>>16)&1u)) >> 16);
}
__device__ __forceinline__ float bf2f(unsigned short h){ return __uint_as_float(((unsigned)h)<<16); }

// ---------------- CSR build (deterministic: atomic scatter + per-segment sort) ----------------
__global__ void k_count(const int* __restrict__ dst, int* __restrict__ cnt){
  int e = blockIdx.x*256+threadIdx.x;
  if (e >= NE) return;
  int d = (e < EE) ? dst[e] : (e - EE);
  atomicAdd(&cnt[d], 1);
}

__global__ __launch_bounds__(1024) void k_scan(const int* __restrict__ cnt, int* __restrict__ ptr){
  __shared__ int part[1024];
  const int n = NN;
  int t = threadIdx.x;
  int base = t*4;
  int loc[4]; int s = 0;
  #pragma unroll
  for (int i=0;i<4;i++){ int c = (base+i < n) ? cnt[base+i] : 0; loc[i] = s; s += c; }
  part[t] = s;
  __syncthreads();
  for (int off=1; off<1024; off<<=1){
    int add = (t >= off) ? part[t-off] : 0;
    __syncthreads();
    part[t] += add;
    __syncthreads();
  }
  int ebase = (t > 0) ? part[t-1] : 0;
  #pragma unroll
  for (int i=0;i<4;i++){ if (base+i < n) ptr[base+i] = ebase + loc[i]; }
  if (t == 1023) ptr[n] = part[1023];
}

__global__ void k_scatter(const int* __restrict__ dst, const int* __restrict__ ptr,
                          int* __restrict__ cur, int* __restrict__ idxa){
  int e = blockIdx.x*256+threadIdx.x;
  if (e >= NE) return;
  int d = (e < EE) ? dst[e] : (e - EE);
  int pos = atomicAdd(&cur[d], 1);
  idxa[ptr[d]+pos] = e;
}

// sort each segment (deterministic order) and emit position-indexed src
__global__ void k_sortseg(const int* __restrict__ ptr, int* __restrict__ idxa,
                          const int* __restrict__ e0, int* __restrict__ srcs){
  int node = blockIdx.x*256+threadIdx.x;
  if (node >= NN) return;
  int p0 = ptr[node], p1 = ptr[node+1];
  for (int i=p0+1;i<p1;i++){
    int key = idxa[i]; int j = i-1;
    while (j >= p0 && idxa[j] > key){ idxa[j+1] = idxa[j]; j--; }
    idxa[j+1] = key;
  }
  for (int p=p0;p<p1;p++){
    int e = idxa[p];
    srcs[p] = (e < EE) ? e0[e] : (e - EE);
  }
}

// ------- merged prep: zero cnt | wtilde | LSTM frags | WfT | GAT Wb frags (bf16 hi/lo) ----------
__global__ void k_prep(int* __restrict__ cnt,
                       const float* __restrict__ W1, const float* __restrict__ as1, const float* __restrict__ ad1,
                       const float* __restrict__ W2, const float* __restrict__ as2, const float* __restrict__ ad2,
                       float* __restrict__ wt,
                       const float* __restrict__ Wih, const float* __restrict__ Whh,
                       unsigned short* __restrict__ wfh, unsigned short* __restrict__ wfl,
                       const float* __restrict__ Wf, float* __restrict__ WfT,
                       unsigned short* __restrict__ wb1h, unsigned short* __restrict__ wb1l,
                       unsigned short* __restrict__ wb2h, unsigned short* __restrict__ wb2l){
  int i = blockIdx.x*256 + threadIdx.x;
  if (i < 2*NN){ cnt[i] = 0; return; }
  i -= 2*NN;
  if (i < 768){
    if (i < 256){                      // layer1 wtilde: sd*128 + h*32 + k
      int sd = i >> 7, h = (i >> 5) & 3, k = i & 31;
      const float* a = sd ? ad1 : as1;
      float s = 0.f;
      for (int c=0;c<CC;c++) s = fmaf(W1[k*HC + h*CC + c], a[h*CC + c], s);
      wt[sd*128 + h*32 + k] = s;
    } else {
      int j = i - 256;
      int sd = j >> 8, h = (j >> 6) & 3, k = j & 63;
      const float* a = sd ? ad2 : as2;
      float s = 0.f;
      for (int c=0;c<CC;c++) s = fmaf(W2[k*HC + h*CC + c], a[h*CC + c], s);
      wt[256 + sd*256 + h*64 + k] = s;
    }
    return;
  }
  i -= 768;
  if (i < 12288){                      // LSTM B-fragments (bf16 hi/lo split)
    int lane = i & 63;
    int kc = (i >> 6) % 6;
    int wk = i / (64*6);
    int w = wk & 7, gg = wk >> 3;
    int n = gg*128 + w*16 + (lane & 15);
    int kbase = kc*32 + (lane >> 4)*8;
    #pragma unroll
    for (int j=0;j<8;j++){
      int k = kbase + j;
      float v = (k < 64) ? Wih[n*64 + k] : Whh[n*128 + (k-64)];
      unsigned short hi = bf16rne(v);
      wfh[(size_t)i*8 + j] = hi;
      wfl[(size_t)i*8 + j] = bf16rne(v - bf2f(hi));
    }
    return;
  }
  i -= 12288;
  if (i < 24576){                      // WfT[u][k] = Wf[k][u]
    int u = i & 127, k = i >> 7;
    WfT[u*192 + k] = Wf[k*128 + u];
    return;
  }
  i -= 24576;
  if (i < 1024){                       // layer1 Wb frags: (nt*4 + kc)*64 + lane, KF=32
    int lane = i & 63, kc = (i >> 6) & 3, nt = i >> 8;
    int n = nt*16 + (lane & 15);
    int kb = kc*32 + (lane >> 4)*8;
    #pragma unroll
    for (int j=0;j<8;j++){
      int k = kb + j; int h = k >> 5; int kk = k & 31;
      float v = W1[kk*HC + h*CC + n];
      unsigned short hi = bf16rne(v);
      wb1h[(size_t)i*8 + j] = hi;
      wb1l[(size_t)i*8 + j] = bf16rne(v - bf2f(hi));
    }
    return;
  }
  i -= 1024;
  if (i < 2048){                       // layer2 Wb frags: (nt*8 + kc)*64 + lane, KF=64
    int lane = i & 63, kc = (i >> 6) & 7, nt = i >> 9;
    int n = nt*16 + (lane & 15);
    int kb = kc*32 + (lane >> 4)*8;
    #pragma unroll
    for (int j=0;j<8;j++){
      int k = kb + j; int h = k >> 6; int kk = k & 63;
      float v = W2[kk*HC + h*CC + n];
      unsigned short hi = bf16rne(v);
      wb2h[(size_t)i*8 + j] = hi;
      wb2l[(size_t)i*8 + j] = bf16rne(v - bf2f(hi));
    }
  }
}

// ---------------- attention coefficients: one thread per (inst,node), all 4 heads ----------------
template<int K>
__global__ void k_coef3(const float* __restrict__ x, const float* __restrict__ wts,
                        const float* __restrict__ wtd,
                        float* __restrict__ als, float* __restrict__ ald){
  int i = blockIdx.x*256+threadIdx.x;          // inst*NN + n
  if (i >= BT*NN) return;
  const float* xp = x + (size_t)i*K;
  float s1[4] = {0.f,0.f,0.f,0.f};
  float s2[4] = {0.f,0.f,0.f,0.f};
  for (int k=0;k<K;k+=4){
    float4 xv = *(const float4*)&xp[k];
    #pragma unroll
    for (int h=0;h<4;h++){
      float4 sv = *(const float4*)&wts[h*K+k];
      float4 dv = *(const float4*)&wtd[h*K+k];
      s1[h] = fmaf(xv.x,sv.x,fmaf(xv.y,sv.y,fmaf(xv.z,sv.z,fmaf(xv.w,sv.w,s1[h]))));
      s2[h] = fmaf(xv.x,dv.x,fmaf(xv.y,dv.y,fmaf(xv.z,dv.z,fmaf(xv.w,dv.w,s2[h]))));
    }
  }
  *(float4*)&als[(size_t)i*4] = make_float4(s1[0],s1[1],s1[2],s1[3]);
  *(float4*)&ald[(size_t)i*4] = make_float4(s2[0],s2[1],s2[2],s2[3]);
}

// ---- fused GAT layer v6: 16-lane group per node, 2-edge unrolled gather loop, MFMA GEMM ---------
template<int KF, bool SPLIT>
__global__ __launch_bounds__(256) void k_gatt(const int* __restrict__ ptr, const int* __restrict__ srcs,
    const float* __restrict__ als, const float* __restrict__ ald, const float* __restrict__ xin,
    const unsigned short* __restrict__ wbh, const unsigned short* __restrict__ wbl,
    const float* __restrict__ bias, float* __restrict__ outp,
    unsigned short* __restrict__ ohi, unsigned short* __restrict__ olo){
  constexpr int K = HH*KF;            // 128 / 256
  constexpr int PR = K + 8;           // padded row in ushorts
  constexpr int NKC = K/32;           // 4 / 8
  constexpr int VPL = KF/16;          // floats per lane: 2 (KF=32) or 4 (KF=64)
  __shared__ unsigned short agh[16*PR];
  __shared__ unsigned short agl[16*PR];
  const int tid = threadIdx.x;
  const int lane = tid & 63;
  const int wv = tid >> 6;
  const int l15 = lane & 15;
  const int lg  = lane >> 4;
  // XCD-clustered remap (dispatch round-robin: bid&7 ~ XCD)
  const int bid = blockIdx.x;
  const int q = bid >> 3;
  const int hi2 = (q >= 250);
  const int inst = (bid & 7) + (hi2 ? 8 : 0);
  const int node0 = (hi2 ? q - 250 : q)*16;
  const size_t ibase = (size_t)inst*NN;
  // ---- Phase A: one node per 16-lane group; 2 edges per iteration (4 loads in flight) ----
  {
    const int nl = wv*4 + lg;
    const int node = node0 + nl;
    const int p0 = ptr[node], p1 = ptr[node+1];
    const float4 adv = *(const float4*)&ald[(ibase+node)*4];
    const float ad[4] = {adv.x, adv.y, adv.z, adv.w};
    float den[4] = {0.f,0.f,0.f,0.f};
    float a[4][VPL];
    #pragma unroll
    for (int h=0;h<4;h++)
      #pragma unroll
      for (int c=0;c<VPL;c++) a[h][c] = 0.f;
    auto ldx = [&](int s, float (&xv)[VPL]){
      if constexpr (VPL == 4){
        float4 x4 = *(const float4*)&xin[(ibase + s)*(size_t)KF + l15*4];
        xv[0]=x4.x; xv[1]=x4.y; xv[2]=x4.z; xv[3]=x4.w;
      } else {
        float2 x2 = *(const float2*)&xin[(ibase + s)*(size_t)KF + l15*2];
        xv[0]=x2.x; xv[1]=x2.y;
      }
    };
    int p = p0;
    for (; p + 2 <= p1; p += 2){
      const int s0 = srcs[p], s1 = srcs[p+1];
      const float4 av0 = *(const float4*)&als[(ibase + s0)*4];
      const float4 av1 = *(const float4*)&als[(ibase + s1)*4];
      float xv0[VPL], xv1[VPL];
      ldx(s0, xv0);
      ldx(s1, xv1);
      const float ac0[4] = {av0.x, av0.y, av0.z, av0.w};
      const float ac1[4] = {av1.x, av1.y, av1.z, av1.w};
      #pragma unroll
      for (int h=0;h<4;h++){
        float v0 = ac0[h] + ad[h];
        v0 = (v0 >= 0.f) ? v0 : 0.2f*v0;
        float e0 = fexp2(v0*1.44269504f);
        float v1 = ac1[h] + ad[h];
        v1 = (v1 >= 0.f) ? v1 : 0.2f*v1;
        float e1 = fexp2(v1*1.44269504f);
        den[h] += e0 + e1;
        #pragma unroll
        for (int c=0;c<VPL;c++)
          a[h][c] = fmaf(e0, xv0[c], fmaf(e1, xv1[c], a[h][c]));
      }
    }
    if (p < p1){                       // tail (odd degree)
      const int s0 = srcs[p];
      const float4 av0 = *(const float4*)&als[(ibase + s0)*4];
      float xv0[VPL];
      ldx(s0, xv0);
      const float ac0[4] = {av0.x, av0.y, av0.z, av0.w};
      #pragma unroll
      for (int h=0;h<4;h++){
        float v0 = ac0[h] + ad[h];
        v0 = (v0 >= 0.f) ? v0 : 0.2f*v0;
        float e0 = fexp2(v0*1.44269504f);
        den[h] += e0;
        #pragma unroll
        for (int c=0;c<VPL;c++) a[h][c] = fmaf(e0, xv0[c], a[h][c]);
      }
    }
    // epilogue per lane: normalize + trunc-split pack (hi exact mask, lo rne)
    #pragma unroll
    for (int h=0;h<4;h++){
      float inv = 0.25f * frcp(den[h]);
      unsigned short vh[VPL], vl[VPL];
      #pragma unroll
      for (int c=0;c<VPL;c++){
        float v = a[h][c]*inv;
        unsigned uh = __float_as_uint(v) & 0xFFFF0000u;
        vh[c] = (unsigned short)(uh >> 16);
        vl[c] = bf16rne(v - __uint_as_float(uh));
      }
      if constexpr (VPL == 4){
        uint2 ph = {((unsigned)vh[1]<<16)|vh[0], ((unsigned)vh[3]<<16)|vh[2]};
        uint2 pl = {((unsigned)vl[1]<<16)|vl[0], ((unsigned)vl[3]<<16)|vl[2]};
        *(uint2*)&agh[nl*PR + h*KF + l15*4] = ph;
        *(uint2*)&agl[nl*PR + h*KF + l15*4] = pl;
      } else {
        *(unsigned*)&agh[nl*PR + h*KF + l15*2] = ((unsigned)vh[1]<<16)|vh[0];
        *(unsigned*)&agl[nl*PR + h*KF + l15*2] = ((unsigned)vl[1]<<16)|vl[0];
      }
    }
  }
  __syncthreads();
  // ---- Phase B: out[16 nodes][64 cols] = aggs @ Wb via 3-term split MFMA ----
  f32x4 acc = {0.f,0.f,0.f,0.f};
  #pragma unroll
  for (int kc=0; kc<NKC; kc++){
    size_t fl = (size_t)((wv*NKC + kc)*64 + lane)*8;
    short8v BH = *(const short8v*)&wbh[fl];
    short8v BL = *(const short8v*)&wbl[fl];
    int aoff = l15*PR + kc*32 + lg*8;
    short8v AH = *(const short8v*)&agh[aoff];
    short8v AL = *(const short8v*)&agl[aoff];
    acc = __builtin_amdgcn_mfma_f32_16x16x32_bf16(AH, BH, acc, 0,0,0);
    acc = __builtin_amdgcn_mfma_f32_16x16x32_bf16(AH, BL, acc, 0,0,0);
    acc = __builtin_amdgcn_mfma_f32_16x16x32_bf16(AL, BH, acc, 0,0,0);
  }
  const int c = wv*16 + l15;
  const float bv = bias[c];
  #pragma unroll
  for (int r=0;r<4;r++){
    int node = node0 + lg*4 + r;
    float val = fmaxf(acc[r] + bv, 0.f);
    size_t oi = (ibase + node)*CC + c;
    if constexpr (SPLIT){
      unsigned short hv = bf16rne(val);
      ohi[oi] = hv;
      olo[oi] = bf16rne(val - bf2f(hv));
    } else {
      outp[oi] = val;
    }
  }
}

// ---------------- MFMA LSTM v11: WhhHI resident in LDS; WhhLO + Wih streamed from L2 ------------
__device__ __forceinline__ void mfma24(const short8v (&AH)[2], const short8v (&AL)[2],
                                       const short8v (&BH)[4], const short8v (&BL)[4],
                                       f32x4 (&acc)[2][4]){
  #pragma unroll
  for (int mt=0;mt<2;mt++)
    #pragma unroll
    for (int gg=0;gg<4;gg++)
      acc[mt][gg] = __builtin_amdgcn_mfma_f32_16x16x32_bf16(AH[mt], BH[gg], acc[mt][gg], 0,0,0);
  #pragma unroll
  for (int mt=0;mt<2;mt++)
    #pragma unroll
    for (int gg=0;gg<4;gg++)
      acc[mt][gg] = __builtin_amdgcn_mfma_f32_16x16x32_bf16(AH[mt], BL[gg], acc[mt][gg], 0,0,0);
  #pragma unroll
  for (int mt=0;mt<2;mt++)
    #pragma unroll
    for (int gg=0;gg<4;gg++)
      acc[mt][gg] = __builtin_amdgcn_mfma_f32_16x16x32_bf16(AL[mt], BH[gg], acc[mt][gg], 0,0,0);
}

__global__ __launch_bounds__(512) void k_lstm11(
    const unsigned short* __restrict__ ghi, const unsigned short* __restrict__ glo,
    const unsigned short* __restrict__ wfh, const unsigned short* __restrict__ wfl,
    const float* __restrict__ bih, const float* __restrict__ bhh,
    const float* __restrict__ WfT, const float* __restrict__ bfv,
    const float* __restrict__ Wo, const float* __restrict__ bo,
    float* __restrict__ out){
  __shared__ unsigned short whhl[128*512];       // 128 KB: WhhHI frags kc2..5 (reused as catf)
  __shared__ unsigned short hbuf[2*32*PADU];     // 17.4 KB: hhi | hlo (reused as red)
  unsigned short* hhi = hbuf;
  unsigned short* hlo = hbuf + 32*PADU;
  const int tid = threadIdx.x;
  const int lane = tid & 63;
  const int wv = tid >> 6;             // 0..7
  const int l15 = lane & 15;
  const int lg  = lane >> 4;           // 0..3
  const int r0 = blockIdx.x*32;
  const int b  = r0 / NN;
  const int n0 = r0 % NN;
  // cooperative preload of WhhHI (kc 2..5) into LDS: local frag f = (gg*8+wv)*4 + kcr
  for (int i = tid; i < 128*64; i += 512){
    int frag = i >> 6, sub = i & 63;
    int gw = frag >> 2, kcr = frag & 3;
    size_t gsrc = ((size_t)(gw*6 + kcr + 2)*64 + sub)*8;
    *(uint4*)&whhl[(size_t)i*8] = *(const uint4*)&wfh[gsrc];
  }
  float bias[4];
  #pragma unroll
  for (int gg=0; gg<4; gg++){
    int n = gg*128 + wv*16 + l15;
    bias[gg] = bih[n] + bhh[n];
  }
  float c01[2][4];
  #pragma unroll
  for (int mt=0;mt<2;mt++)
    #pragma unroll
    for (int r=0;r<4;r++) c01[mt][r]=0.f;
  __syncthreads();

  auto ldwx = [&](int kc, short8v (&BH)[4], short8v (&BL)[4]){    // Wih: global hi+lo
    #pragma unroll
    for (int gg=0;gg<4;gg++){
      size_t fl = (size_t)(((gg*8+wv)*6 + kc)*64 + lane)*8;
      BH[gg] = *(const short8v*)&wfh[fl];
      BL[gg] = *(const short8v*)&wfl[fl];
    }
  };
  auto ldwh = [&](int kcr, short8v (&BH)[4], short8v (&BL)[4]){   // Whh: LDS hi, global lo
    #pragma unroll
    for (int gg=0;gg<4;gg++){
      size_t lf = (size_t)(((gg*8+wv)*4 + kcr)*64 + lane)*8;
      BH[gg] = *(const short8v*)&whhl[lf];
      size_t fl = (size_t)(((gg*8+wv)*6 + kcr + 2)*64 + lane)*8;
      BL[gg] = *(const short8v*)&wfl[fl];
    }
  };

  for (int t=0;t<TT;t++){
    short8v axH[2][2], axL[2][2];
    #pragma unroll
    for (int mt=0; mt<2; mt++){
      const size_t row = ((size_t)(b*TT+t)*NN + n0 + mt*16 + l15);
      #pragma unroll
      for (int kc=0; kc<2; kc++){
        size_t off = row*64 + kc*32 + lg*8;
        axH[mt][kc] = *(const short8v*)&ghi[off];
        axL[mt][kc] = *(const short8v*)&glo[off];
      }
    }
    auto ldah = [&](int kcr, short8v (&AH)[2], short8v (&AL)[2]){
      #pragma unroll
      for (int mt=0;mt<2;mt++){
        int off = (mt*16 + l15)*PADU + kcr*32 + lg*8;
        AH[mt] = *(const short8v*)&hhi[off];
        AL[mt] = *(const short8v*)&hlo[off];
      }
    };
    f32x4 acc[2][4];
    #pragma unroll
    for (int mt=0;mt<2;mt++){
      #pragma unroll
      for (int gg=0;gg<4;gg++){
        acc[mt][gg][0]=bias[gg]; acc[mt][gg][1]=bias[gg];
        acc[mt][gg][2]=bias[gg]; acc[mt][gg][3]=bias[gg];
      }
    }
    short8v BHa[4], BLa[4], BHb[4], BLb[4], AH[2], AL[2];
    if (t == 0){
      ldwx(0, BHa, BLa);
      ldwx(1, BHb, BLb);
      AH[0]=axH[0][0]; AH[1]=axH[1][0]; AL[0]=axL[0][0]; AL[1]=axL[1][0];
      mfma24(AH, AL, BHa, BLa, acc);
      AH[0]=axH[0][1]; AH[1]=axH[1][1]; AL[0]=axL[0][1]; AL[1]=axL[1][1];
      mfma24(AH, AL, BHb, BLb, acc);
    } else {
      ldwx(0, BHa, BLa);
      ldwx(1, BHb, BLb);
      AH[0]=axH[0][0]; AH[1]=axH[1][0]; AL[0]=axL[0][0]; AL[1]=axL[1][0];
      mfma24(AH, AL, BHa, BLa, acc);
      ldwh(0, BHa, BLa);
      AH[0]=axH[0][1]; AH[1]=axH[1][1]; AL[0]=axL[0][1]; AL[1]=axL[1][1];
      mfma24(AH, AL, BHb, BLb, acc);
      ldwh(1, BHb, BLb);
      ldah(0, AH, AL); mfma24(AH, AL, BHa, BLa, acc);
      ldwh(2, BHa, BLa);
      ldah(1, AH, AL); mfma24(AH, AL, BHb, BLb, acc);
      ldwh(3, BHb, BLb);
      ldah(2, AH, AL); mfma24(AH, AL, BHa, BLa, acc);
      ldah(3, AH, AL); mfma24(AH, AL, BHb, BLb, acc);
    }
    // gates (i,f,g,o), thread-local
    unsigned short hh_[2][4], hl_[2][4];
    #pragma unroll
    for (int mt=0;mt<2;mt++){
      #pragma unroll
      for (int r=0;r<4;r++){
        float zi = acc[mt][0][r], zf = acc[mt][1][r], zg = acc[mt][2][r], zo = acc[mt][3][r];
        float cv = fsig(zf)*c01[mt][r] + fsig(zi)*ftanh(zg);
        c01[mt][r] = cv;
        float hv = fsig(zo)*ftanh(cv);
        unsigned short hi = bf16rne(hv);
        hh_[mt][r] = hi;
        hl_[mt][r] = bf16rne(hv - bf2f(hi));
      }
    }
    if (t > 0) __syncthreads();        // all reads of h(t) complete before overwrite
    #pragma unroll
    for (int mt=0;mt<2;mt++){
      #pragma unroll
      for (int r=0;r<4;r++){
        int m = mt*16 + lg*4 + r;
        int u = wv*16 + l15;
        hhi[m*PADU + u] = hh_[mt][r];
        hlo[m*PADU + u] = hl_[mt][r];
      }
    }
    __syncthreads();
  }
  // ---- epilogue: rebuild catf in (now-dead) whhl, then fused MLP ----
  float* catf = (float*)whhl;          // 32 x PADC fp32 (25 KB << 128 KB)
  {
    const size_t grow = ((size_t)(b*TT+TT-1)*NN + n0)*CC;
    for (int i = tid; i < 32*192; i += 512){
      int m = i / 192, k = i - m*192;
      float v;
      if (k < 128) v = bf2f(hhi[m*PADU + k]) + bf2f(hlo[m*PADU + k]);
      else {
        size_t gi = grow + (size_t)m*CC + (k-128);
        v = bf2f(ghi[gi]) + bf2f(glo[gi]);
      }
      catf[m*PADC + k] = v;
    }
  }
  __syncthreads();
  const int u = tid & 127;
  const int rg = tid >> 7;
  float fa[8];
  #pragma unroll
  for (int r=0;r<8;r++) fa[r] = bfv[u];
  for (int k4=0;k4<48;k4++){
    float4 wf = *(const float4*)&WfT[u*192 + k4*4];
    #pragma unroll
    for (int r=0;r<8;r++){
      float4 cv = *(const float4*)&catf[(rg*8+r)*PADC + k4*4];
      fa[r] = fmaf(cv.x,wf.x,fmaf(cv.y,wf.y,fmaf(cv.z,wf.z,fmaf(cv.w,wf.w,fa[r]))));
    }
  }
  float wo = Wo[u];
  #pragma unroll
  for (int r=0;r<8;r++) fa[r] = fmaxf(fa[r], 0.f) * wo;
  __syncthreads();                     // all catf/hbuf reads done before red overwrite
  float* red = (float*)hbuf;           // 16 KB fits in 17.4 KB
  #pragma unroll
  for (int r=0;r<8;r++) red[(rg*8+r)*FHN + u] = fa[r];
  __syncthreads();
  for (int s=64;s>=1;s>>=1){
    if (u < s){
      #pragma unroll
      for (int r=0;r<8;r++) red[(rg*8+r)*FHN + u] += red[(rg*8+r)*FHN + u + s];
    }
    __syncthreads();
  }
  if (u == 0){
    #pragma unroll
    for (int r=0;r<8;r++) out[r0 + rg*8 + r] = red[(rg*8+r)*FHN] + bo[0];
  }
}

// ---------------- launch ----------------
extern "C" void kernel_launch(void* const* d_in, const int* in_sizes, int n_in,
                              void* d_out, int out_size, void* d_ws, size_t ws_size,
                              hipStream_t stream) {
  const float* x_seq  = (const float*)d_in[0];
  const float* W1     = (const float*)d_in[1];
  const float* a_src1 = (const float*)d_in[2];
  const float* a_dst1 = (const float*)d_in[3];
  const float* b1     = (const float*)d_in[4];
  const float* W2     = (const float*)d_in[5];
  const float* a_src2 = (const float*)d_in[6];
  const float* a_dst2 = (const float*)d_in[7];
  const float* b2     = (const float*)d_in[8];
  const float* W_ih   = (const float*)d_in[9];
  const float* W_hh   = (const float*)d_in[10];
  const float* b_ih   = (const float*)d_in[11];
  const float* b_hh   = (const float*)d_in[12];
  const float* Wf     = (const float*)d_in[13];
  const float* bfv    = (const float*)d_in[14];
  const float* Wo     = (const float*)d_in[15];
  const float* bo     = (const float*)d_in[16];
  const int*   ei     = (const int*)d_in[17];
  const int* e_src = ei;
  const int* e_dst = ei + EE;
  float* out = (float*)d_out;

  char* w = (char*)d_ws;
  auto alloc = [&](size_t bytes)->char*{
    char* p = w; w += (bytes + 255) & ~(size_t)255; return p;
  };
  float* als   = (float*)alloc((size_t)BT*NN*HH*4);
  float* ald   = (float*)alloc((size_t)BT*NN*HH*4);
  float* gat1  = (float*)alloc((size_t)BT*NN*CC*4);                 // layer1 out fp32
  unsigned short* ghi = (unsigned short*)alloc((size_t)BT*NN*CC*2); // layer2 out bf16-hi
  unsigned short* glo = (unsigned short*)alloc((size_t)BT*NN*CC*2); // layer2 out bf16-lo
  unsigned short* wfh = (unsigned short*)alloc((size_t)12288*8*2);  // LSTM W frag hi
  unsigned short* wfl = (unsigned short*)alloc((size_t)12288*8*2);  // LSTM W frag lo
  unsigned short* wb1h = (unsigned short*)alloc((size_t)1024*8*2);  // GAT1 Wb frag hi
  unsigned short* wb1l = (unsigned short*)alloc((size_t)1024*8*2);
  unsigned short* wb2h = (unsigned short*)alloc((size_t)2048*8*2);  // GAT2 Wb frag hi
  unsigned short* wb2l = (unsigned short*)alloc((size_t)2048*8*2);
  float* WfT   = (float*)alloc((size_t)128*192*4);
  float* wt    = (float*)alloc((size_t)768*4);
  int* cnt     = (int*)alloc((size_t)2*NN*4);
  int* cur     = cnt + NN;
  int* ptr     = (int*)alloc((size_t)(NN+1)*4);
  int* idxa    = (int*)alloc((size_t)NE*4);
  int* srcs    = (int*)alloc((size_t)NE*4);

  // merged prep
  k_prep<<<(2*NN+768+12288+24576+1024+2048+255)/256, 256, 0, stream>>>(
      cnt, W1, a_src1, a_dst1, W2, a_src2, a_dst2, wt, W_ih, W_hh, wfh, wfl, Wf, WfT,
      wb1h, wb1l, wb2h, wb2l);
  // CSR build (same graph for all 16 instances)
  k_count<<<(NE+255)/256, 256, 0, stream>>>(e_dst, cnt);
  k_scan<<<1, 1024, 0, stream>>>(cnt, ptr);
  k_scatter<<<(NE+255)/256, 256, 0, stream>>>(e_dst, ptr, cur, idxa);
  k_sortseg<<<(NN+255)/256, 256, 0, stream>>>(ptr, idxa, e_src, srcs);

  // GAT layer 1 (32-dim x-space agg, 2-edge unrolled gather)
  k_coef3<32><<<(BT*NN+255)/256, 256, 0, stream>>>(x_seq, wt, wt+128, als, ald);
  k_gatt<32,false><<<4000, 256, 0, stream>>>(ptr, srcs, als, ald, x_seq, wb1h, wb1l, b1,
                                             gat1, nullptr, nullptr);
  // GAT layer 2 (64-dim) — emits bf16-split g only
  k_coef3<64><<<(BT*NN+255)/256, 256, 0, stream>>>(gat1, wt+256, wt+512, als, ald);
  k_gatt<64,true><<<4000, 256, 0, stream>>>(ptr, srcs, als, ald, gat1, wb2h, wb2l, b2,
                                            nullptr, ghi, glo);

  // MFMA LSTM + fused output MLP (WhhHI LDS-resident)
  k_lstm11<<<BB*NN/32, 512, 0, stream>>>(ghi, glo, wfh, wfl, b_ih, b_hh, WfT, bfv, Wo, bo, out);
}

// Round 20
// 211.365 us; speedup vs baseline: 1.2293x; 1.0022x over previous
//
#include <hip/hip_runtime.h>
#include <math.h>

#define NN 4000
#define EE 40000
#define NE 44000   // EE + NN self-loops
#define BB 2
#define TT 8
#define BT 16      // B*T graph instances
#define HH 4
#define CC 64
#define HC 256     // H*C
#define HLN 128    // lstm hidden
#define G4 512     // 4*HLN
#define FHN 128
#define PADU 136   // ushort pad for h LDS rows
#define PADC 196   // fp32 pad for cat LDS rows

typedef __attribute__((ext_vector_type(8))) short short8v;
typedef __attribute__((ext_vector_type(4))) float f32x4;

__device__ __forceinline__ float fexp2(float x){ return __builtin_amdgcn_exp2f(x); }
__device__ __forceinline__ float frcp(float x){ return __builtin_amdgcn_rcpf(x); }
__device__ __forceinline__ float fsig(float x){ return frcp(1.f + fexp2(x * -1.44269504f)); }
__device__ __forceinline__ float ftanh(float x){
  float xx = fminf(fmaxf(x, -10.f), 10.f);
  float e = fexp2(xx * 2.88539008f);
  return (e - 1.f) * frcp(e + 1.f);
}
__device__ __forceinline__ unsigned short bf16rne(float x){
  unsigned u = __float_as_uint(x);
  return (unsigned short)((u + 0x7FFFu + ((u>>16)&1u)) >> 16);
}
__device__ __forceinline__ float bf2f(unsigned short h){ return __uint_as_float(((unsigned)h)<<16); }

// ---------------- CSR build (deterministic: atomic scatter + per-segment sort) ----------------
__global__ void k_count(const int* __restrict__ dst, int* __restrict__ cnt){
  int e = blockIdx.x*256+threadIdx.x;
  if (e >= NE) return;
  int d = (e < EE) ? dst[e] : (e - EE);
  atomicAdd(&cnt[d], 1);
}

__global__ __launch_bounds__(1024) void k_scan(const int* __restrict__ cnt, int* __restrict__ ptr){
  __shared__ int part[1024];
  const int n = NN;
  int t = threadIdx.x;
  int base = t*4;
  int loc[4]; int s = 0;
  #pragma unroll
  for (int i=0;i<4;i++){ int c = (base+i < n) ? cnt[base+i] : 0; loc[i] = s; s += c; }
  part[t] = s;
  __syncthreads();
  for (int off=1; off<1024; off<<=1){
    int add = (t >= off) ? part[t-off] : 0;
    __syncthreads();
    part[t] += add;
    __syncthreads();
  }
  int ebase = (t > 0) ? part[t-1] : 0;
  #pragma unroll
  for (int i=0;i<4;i++){ if (base+i < n) ptr[base+i] = ebase + loc[i]; }
  if (t == 1023) ptr[n] = part[1023];
}

__global__ void k_scatter(const int* __restrict__ dst, const int* __restrict__ ptr,
                          int* __restrict__ cur, int* __restrict__ idxa){
  int e = blockIdx.x*256+threadIdx.x;
  if (e >= NE) return;
  int d = (e < EE) ? dst[e] : (e - EE);
  int pos = atomicAdd(&cur[d], 1);
  idxa[ptr[d]+pos] = e;
}

// sort each segment (deterministic order) and emit position-indexed src
__global__ void k_sortseg(const int* __restrict__ ptr, int* __restrict__ idxa,
                          const int* __restrict__ e0, int* __restrict__ srcs){
  int node = blockIdx.x*256+threadIdx.x;
  if (node >= NN) return;
  int p0 = ptr[node], p1 = ptr[node+1];
  for (int i=p0+1;i<p1;i++){
    int key = idxa[i]; int j = i-1;
    while (j >= p0 && idxa[j] > key){ idxa[j+1] = idxa[j]; j--; }
    idxa[j+1] = key;
  }
  for (int p=p0;p<p1;p++){
    int e = idxa[p];
    srcs[p] = (e < EE) ? e0[e] : (e - EE);
  }
}

// ------- merged prep: zero cnt | wtilde | LSTM frags | WfT | GAT Wb frags (bf16 hi/lo) ----------
__global__ void k_prep(int* __restrict__ cnt,
                       const float* __restrict__ W1, const float* __restrict__ as1, const float* __restrict__ ad1,
                       const float* __restrict__ W2, const float* __restrict__ as2, const float* __restrict__ ad2,
                       float* __restrict__ wt,
                       const float* __restrict__ Wih, const float* __restrict__ Whh,
                       unsigned short* __restrict__ wfh, unsigned short* __restrict__ wfl,
                       const float* __restrict__ Wf, float* __restrict__ WfT,
                       unsigned short* __restrict__ wb1h, unsigned short* __restrict__ wb1l,
                       unsigned short* __restrict__ wb2h, unsigned short* __restrict__ wb2l){
  int i = blockIdx.x*256 + threadIdx.x;
  if (i < 2*NN){ cnt[i] = 0; return; }
  i -= 2*NN;
  if (i < 768){
    if (i < 256){                      // layer1 wtilde: sd*128 + h*32 + k
      int sd = i >> 7, h = (i >> 5) & 3, k = i & 31;
      const float* a = sd ? ad1 : as1;
      float s = 0.f;
      for (int c=0;c<CC;c++) s = fmaf(W1[k*HC + h*CC + c], a[h*CC + c], s);
      wt[sd*128 + h*32 + k] = s;
    } else {
      int j = i - 256;
      int sd = j >> 8, h = (j >> 6) & 3, k = j & 63;
      const float* a = sd ? ad2 : as2;
      float s = 0.f;
      for (int c=0;c<CC;c++) s = fmaf(W2[k*HC + h*CC + c], a[h*CC + c], s);
      wt[256 + sd*256 + h*64 + k] = s;
    }
    return;
  }
  i -= 768;
  if (i < 12288){                      // LSTM B-fragments (bf16 hi/lo split)
    int lane = i & 63;
    int kc = (i >> 6) % 6;
    int wk = i / (64*6);
    int w = wk & 7, gg = wk >> 3;
    int n = gg*128 + w*16 + (lane & 15);
    int kbase = kc*32 + (lane >> 4)*8;
    #pragma unroll
    for (int j=0;j<8;j++){
      int k = kbase + j;
      float v = (k < 64) ? Wih[n*64 + k] : Whh[n*128 + (k-64)];
      unsigned short hi = bf16rne(v);
      wfh[(size_t)i*8 + j] = hi;
      wfl[(size_t)i*8 + j] = bf16rne(v - bf2f(hi));
    }
    return;
  }
  i -= 12288;
  if (i < 24576){                      // WfT[u][k] = Wf[k][u]
    int u = i & 127, k = i >> 7;
    WfT[u*192 + k] = Wf[k*128 + u];
    return;
  }
  i -= 24576;
  if (i < 1024){                       // layer1 Wb frags: (nt*4 + kc)*64 + lane, KF=32
    int lane = i & 63, kc = (i >> 6) & 3, nt = i >> 8;
    int n = nt*16 + (lane & 15);
    int kb = kc*32 + (lane >> 4)*8;
    #pragma unroll
    for (int j=0;j<8;j++){
      int k = kb + j; int h = k >> 5; int kk = k & 31;
      float v = W1[kk*HC + h*CC + n];
      unsigned short hi = bf16rne(v);
      wb1h[(size_t)i*8 + j] = hi;
      wb1l[(size_t)i*8 + j] = bf16rne(v - bf2f(hi));
    }
    return;
  }
  i -= 1024;
  if (i < 2048){                       // layer2 Wb frags: (nt*8 + kc)*64 + lane, KF=64
    int lane = i & 63, kc = (i >> 6) & 7, nt = i >> 9;
    int n = nt*16 + (lane & 15);
    int kb = kc*32 + (lane >> 4)*8;
    #pragma unroll
    for (int j=0;j<8;j++){
      int k = kb + j; int h = k >> 6; int kk = k & 63;
      float v = W2[kk*HC + h*CC + n];
      unsigned short hi = bf16rne(v);
      wb2h[(size_t)i*8 + j] = hi;
      wb2l[(size_t)i*8 + j] = bf16rne(v - bf2f(hi));
    }
  }
}

// ---------------- attention coefficients: one thread per (inst,node), all 4 heads ----------------
template<int K>
__global__ void k_coef3(const float* __restrict__ x, const float* __restrict__ wts,
                        const float* __restrict__ wtd,
                        float* __restrict__ als, float* __restrict__ ald){
  int i = blockIdx.x*256+threadIdx.x;          // inst*NN + n
  if (i >= BT*NN) return;
  const float* xp = x + (size_t)i*K;
  float s1[4] = {0.f,0.f,0.f,0.f};
  float s2[4] = {0.f,0.f,0.f,0.f};
  for (int k=0;k<K;k+=4){
    float4 xv = *(const float4*)&xp[k];
    #pragma unroll
    for (int h=0;h<4;h++){
      float4 sv = *(const float4*)&wts[h*K+k];
      float4 dv = *(const float4*)&wtd[h*K+k];
      s1[h] = fmaf(xv.x,sv.x,fmaf(xv.y,sv.y,fmaf(xv.z,sv.z,fmaf(xv.w,sv.w,s1[h]))));
      s2[h] = fmaf(xv.x,dv.x,fmaf(xv.y,dv.y,fmaf(xv.z,dv.z,fmaf(xv.w,dv.w,s2[h]))));
    }
  }
  *(float4*)&als[(size_t)i*4] = make_float4(s1[0],s1[1],s1[2],s1[3]);
  *(float4*)&ald[(size_t)i*4] = make_float4(s2[0],s2[1],s2[2],s2[3]);
}

// ---- fused GAT layer v7: 16-lane group per node, 4-edge unrolled gather loop, MFMA GEMM ---------
template<int KF, bool SPLIT>
__global__ __launch_bounds__(256) void k_gatt(const int* __restrict__ ptr, const int* __restrict__ srcs,
    const float* __restrict__ als, const float* __restrict__ ald, const float* __restrict__ xin,
    const unsigned short* __restrict__ wbh, const unsigned short* __restrict__ wbl,
    const float* __restrict__ bias, float* __restrict__ outp,
    unsigned short* __restrict__ ohi, unsigned short* __restrict__ olo){
  constexpr int K = HH*KF;            // 128 / 256
  constexpr int PR = K + 8;           // padded row in ushorts
  constexpr int NKC = K/32;           // 4 / 8
  constexpr int VPL = KF/16;          // floats per lane: 2 (KF=32) or 4 (KF=64)
  __shared__ unsigned short agh[16*PR];
  __shared__ unsigned short agl[16*PR];
  const int tid = threadIdx.x;
  const int lane = tid & 63;
  const int wv = tid >> 6;
  const int l15 = lane & 15;
  const int lg  = lane >> 4;
  // XCD-clustered remap (dispatch round-robin: bid&7 ~ XCD)
  const int bid = blockIdx.x;
  const int q = bid >> 3;
  const int hi2 = (q >= 250);
  const int inst = (bid & 7) + (hi2 ? 8 : 0);
  const int node0 = (hi2 ? q - 250 : q)*16;
  const size_t ibase = (size_t)inst*NN;
  // ---- Phase A: one node per 16-lane group; 4 edges per iteration (8 loads in flight) ----
  {
    const int nl = wv*4 + lg;
    const int node = node0 + nl;
    const int p0 = ptr[node], p1 = ptr[node+1];
    const float4 adv = *(const float4*)&ald[(ibase+node)*4];
    const float ad[4] = {adv.x, adv.y, adv.z, adv.w};
    float den[4] = {0.f,0.f,0.f,0.f};
    float a[4][VPL];
    #pragma unroll
    for (int h=0;h<4;h++)
      #pragma unroll
      for (int c=0;c<VPL;c++) a[h][c] = 0.f;
    auto ldx = [&](int s, float (&xv)[VPL]){
      if constexpr (VPL == 4){
        float4 x4 = *(const float4*)&xin[(ibase + s)*(size_t)KF + l15*4];
        xv[0]=x4.x; xv[1]=x4.y; xv[2]=x4.z; xv[3]=x4.w;
      } else {
        float2 x2 = *(const float2*)&xin[(ibase + s)*(size_t)KF + l15*2];
        xv[0]=x2.x; xv[1]=x2.y;
      }
    };
    auto acc1 = [&](const float4 &av, const float (&xv)[VPL]){
      const float ac[4] = {av.x, av.y, av.z, av.w};
      #pragma unroll
      for (int h=0;h<4;h++){
        float v = ac[h] + ad[h];
        v = (v >= 0.f) ? v : 0.2f*v;
        float e = fexp2(v*1.44269504f);     // logits bounded (weights 0.05-scale): no max-sub
        den[h] += e;
        #pragma unroll
        for (int c=0;c<VPL;c++) a[h][c] = fmaf(e, xv[c], a[h][c]);
      }
    };
    int p = p0;
    for (; p + 4 <= p1; p += 4){
      const int s0 = srcs[p], s1 = srcs[p+1], s2 = srcs[p+2], s3 = srcs[p+3];
      const float4 av0 = *(const float4*)&als[(ibase + s0)*4];
      const float4 av1 = *(const float4*)&als[(ibase + s1)*4];
      const float4 av2 = *(const float4*)&als[(ibase + s2)*4];
      const float4 av3 = *(const float4*)&als[(ibase + s3)*4];
      float xv0[VPL], xv1[VPL], xv2[VPL], xv3[VPL];
      ldx(s0, xv0); ldx(s1, xv1); ldx(s2, xv2); ldx(s3, xv3);
      acc1(av0, xv0); acc1(av1, xv1); acc1(av2, xv2); acc1(av3, xv3);
    }
    for (; p + 2 <= p1; p += 2){
      const int s0 = srcs[p], s1 = srcs[p+1];
      const float4 av0 = *(const float4*)&als[(ibase + s0)*4];
      const float4 av1 = *(const float4*)&als[(ibase + s1)*4];
      float xv0[VPL], xv1[VPL];
      ldx(s0, xv0); ldx(s1, xv1);
      acc1(av0, xv0); acc1(av1, xv1);
    }
    if (p < p1){
      const int s0 = srcs[p];
      const float4 av0 = *(const float4*)&als[(ibase + s0)*4];
      float xv0[VPL];
      ldx(s0, xv0);
      acc1(av0, xv0);
    }
    // epilogue per lane: normalize + trunc-split pack (hi exact mask, lo rne)
    #pragma unroll
    for (int h=0;h<4;h++){
      float inv = 0.25f * frcp(den[h]);
      unsigned short vh[VPL], vl[VPL];
      #pragma unroll
      for (int c=0;c<VPL;c++){
        float v = a[h][c]*inv;
        unsigned uh = __float_as_uint(v) & 0xFFFF0000u;
        vh[c] = (unsigned short)(uh >> 16);
        vl[c] = bf16rne(v - __uint_as_float(uh));
      }
      if constexpr (VPL == 4){
        uint2 ph = {((unsigned)vh[1]<<16)|vh[0], ((unsigned)vh[3]<<16)|vh[2]};
        uint2 pl = {((unsigned)vl[1]<<16)|vl[0], ((unsigned)vl[3]<<16)|vl[2]};
        *(uint2*)&agh[nl*PR + h*KF + l15*4] = ph;
        *(uint2*)&agl[nl*PR + h*KF + l15*4] = pl;
      } else {
        *(unsigned*)&agh[nl*PR + h*KF + l15*2] = ((unsigned)vh[1]<<16)|vh[0];
        *(unsigned*)&agl[nl*PR + h*KF + l15*2] = ((unsigned)vl[1]<<16)|vl[0];
      }
    }
  }
  __syncthreads();
  // ---- Phase B: out[16 nodes][64 cols] = aggs @ Wb via 3-term split MFMA ----
  f32x4 acc = {0.f,0.f,0.f,0.f};
  #pragma unroll
  for (int kc=0; kc<NKC; kc++){
    size_t fl = (size_t)((wv*NKC + kc)*64 + lane)*8;
    short8v BH = *(const short8v*)&wbh[fl];
    short8v BL = *(const short8v*)&wbl[fl];
    int aoff = l15*PR + kc*32 + lg*8;
    short8v AH = *(const short8v*)&agh[aoff];
    short8v AL = *(const short8v*)&agl[aoff];
    acc = __builtin_amdgcn_mfma_f32_16x16x32_bf16(AH, BH, acc, 0,0,0);
    acc = __builtin_amdgcn_mfma_f32_16x16x32_bf16(AH, BL, acc, 0,0,0);
    acc = __builtin_amdgcn_mfma_f32_16x16x32_bf16(AL, BH, acc, 0,0,0);
  }
  const int c = wv*16 + l15;
  const float bv = bias[c];
  #pragma unroll
  for (int r=0;r<4;r++){
    int node = node0 + lg*4 + r;
    float val = fmaxf(acc[r] + bv, 0.f);
    size_t oi = (ibase + node)*CC + c;
    if constexpr (SPLIT){
      unsigned short hv = bf16rne(val);
      ohi[oi] = hv;
      olo[oi] = bf16rne(val - bf2f(hv));
    } else {
      outp[oi] = val;
    }
  }
}

// ---------------- MFMA LSTM v11: WhhHI resident in LDS; WhhLO + Wih streamed from L2 ------------
__device__ __forceinline__ void mfma24(const short8v (&AH)[2], const short8v (&AL)[2],
                                       const short8v (&BH)[4], const short8v (&BL)[4],
                                       f32x4 (&acc)[2][4]){
  #pragma unroll
  for (int mt=0;mt<2;mt++)
    #pragma unroll
    for (int gg=0;gg<4;gg++)
      acc[mt][gg] = __builtin_amdgcn_mfma_f32_16x16x32_bf16(AH[mt], BH[gg], acc[mt][gg], 0,0,0);
  #pragma unroll
  for (int mt=0;mt<2;mt++)
    #pragma unroll
    for (int gg=0;gg<4;gg++)
      acc[mt][gg] = __builtin_amdgcn_mfma_f32_16x16x32_bf16(AH[mt], BL[gg], acc[mt][gg], 0,0,0);
  #pragma unroll
  for (int mt=0;mt<2;mt++)
    #pragma unroll
    for (int gg=0;gg<4;gg++)
      acc[mt][gg] = __builtin_amdgcn_mfma_f32_16x16x32_bf16(AL[mt], BH[gg], acc[mt][gg], 0,0,0);
}

__global__ __launch_bounds__(512) void k_lstm11(
    const unsigned short* __restrict__ ghi, const unsigned short* __restrict__ glo,
    const unsigned short* __restrict__ wfh, const unsigned short* __restrict__ wfl,
    const float* __restrict__ bih, const float* __restrict__ bhh,
    const float* __restrict__ WfT, const float* __restrict__ bfv,
    const float* __restrict__ Wo, const float* __restrict__ bo,
    float* __restrict__ out){
  __shared__ unsigned short whhl[128*512];       // 128 KB: WhhHI frags kc2..5 (reused as catf)
  __shared__ unsigned short hbuf[2*32*PADU];     // 17.4 KB: hhi | hlo (reused as red)
  unsigned short* hhi = hbuf;
  unsigned short* hlo = hbuf + 32*PADU;
  const int tid = threadIdx.x;
  const int lane = tid & 63;
  const int wv = tid >> 6;             // 0..7
  const int l15 = lane & 15;
  const int lg  = lane >> 4;           // 0..3
  const int r0 = blockIdx.x*32;
  const int b  = r0 / NN;
  const int n0 = r0 % NN;
  // cooperative preload of WhhHI (kc 2..5) into LDS: local frag f = (gg*8+wv)*4 + kcr
  for (int i = tid; i < 128*64; i += 512){
    int frag = i >> 6, sub = i & 63;
    int gw = frag >> 2, kcr = frag & 3;
    size_t gsrc = ((size_t)(gw*6 + kcr + 2)*64 + sub)*8;
    *(uint4*)&whhl[(size_t)i*8] = *(const uint4*)&wfh[gsrc];
  }
  float bias[4];
  #pragma unroll
  for (int gg=0; gg<4; gg++){
    int n = gg*128 + wv*16 + l15;
    bias[gg] = bih[n] + bhh[n];
  }
  float c01[2][4];
  #pragma unroll
  for (int mt=0;mt<2;mt++)
    #pragma unroll
    for (int r=0;r<4;r++) c01[mt][r]=0.f;
  __syncthreads();

  auto ldwx = [&](int kc, short8v (&BH)[4], short8v (&BL)[4]){    // Wih: global hi+lo
    #pragma unroll
    for (int gg=0;gg<4;gg++){
      size_t fl = (size_t)(((gg*8+wv)*6 + kc)*64 + lane)*8;
      BH[gg] = *(const short8v*)&wfh[fl];
      BL[gg] = *(const short8v*)&wfl[fl];
    }
  };
  auto ldwh = [&](int kcr, short8v (&BH)[4], short8v (&BL)[4]){   // Whh: LDS hi, global lo
    #pragma unroll
    for (int gg=0;gg<4;gg++){
      size_t lf = (size_t)(((gg*8+wv)*4 + kcr)*64 + lane)*8;
      BH[gg] = *(const short8v*)&whhl[lf];
      size_t fl = (size_t)(((gg*8+wv)*6 + kcr + 2)*64 + lane)*8;
      BL[gg] = *(const short8v*)&wfl[fl];
    }
  };

  for (int t=0;t<TT;t++){
    short8v axH[2][2], axL[2][2];
    #pragma unroll
    for (int mt=0; mt<2; mt++){
      const size_t row = ((size_t)(b*TT+t)*NN + n0 + mt*16 + l15);
      #pragma unroll
      for (int kc=0; kc<2; kc++){
        size_t off = row*64 + kc*32 + lg*8;
        axH[mt][kc] = *(const short8v*)&ghi[off];
        axL[mt][kc] = *(const short8v*)&glo[off];
      }
    }
    auto ldah = [&](int kcr, short8v (&AH)[2], short8v (&AL)[2]){
      #pragma unroll
      for (int mt=0;mt<2;mt++){
        int off = (mt*16 + l15)*PADU + kcr*32 + lg*8;
        AH[mt] = *(const short8v*)&hhi[off];
        AL[mt] = *(const short8v*)&hlo[off];
      }
    };
    f32x4 acc[2][4];
    #pragma unroll
    for (int mt=0;mt<2;mt++){
      #pragma unroll
      for (int gg=0;gg<4;gg++){
        acc[mt][gg][0]=bias[gg]; acc[mt][gg][1]=bias[gg];
        acc[mt][gg][2]=bias[gg]; acc[mt][gg][3]=bias[gg];
      }
    }
    short8v BHa[4], BLa[4], BHb[4], BLb[4], AH[2], AL[2];
    if (t == 0){
      ldwx(0, BHa, BLa);
      ldwx(1, BHb, BLb);
      AH[0]=axH[0][0]; AH[1]=axH[1][0]; AL[0]=axL[0][0]; AL[1]=axL[1][0];
      mfma24(AH, AL, BHa, BLa, acc);
      AH[0]=axH[0][1]; AH[1]=axH[1][1]; AL[0]=axL[0][1]; AL[1]=axL[1][1];
      mfma24(AH, AL, BHb, BLb, acc);
    } else {
      ldwx(0, BHa, BLa);
      ldwx(1, BHb, BLb);
      AH[0]=axH[0][0]; AH[1]=axH[1][0]; AL[0]=axL[0][0]; AL[1]=axL[1][0];
      mfma24(AH, AL, BHa, BLa, acc);
      ldwh(0, BHa, BLa);
      AH[0]=axH[0][1]; AH[1]=axH[1][1]; AL[0]=axL[0][1]; AL[1]=axL[1][1];
      mfma24(AH, AL, BHb, BLb, acc);
      ldwh(1, BHb, BLb);
      ldah(0, AH, AL); mfma24(AH, AL, BHa, BLa, acc);
      ldwh(2, BHa, BLa);
      ldah(1, AH, AL); mfma24(AH, AL, BHb, BLb, acc);
      ldwh(3, BHb, BLb);
      ldah(2, AH, AL); mfma24(AH, AL, BHa, BLa, acc);
      ldah(3, AH, AL); mfma24(AH, AL, BHb, BLb, acc);
    }
    // gates (i,f,g,o), thread-local
    unsigned short hh_[2][4], hl_[2][4];
    #pragma unroll
    for (int mt=0;mt<2;mt++){
      #pragma unroll
      for (int r=0;r<4;r++){
        float zi = acc[mt][0][r], zf = acc[mt][1][r], zg = acc[mt][2][r], zo = acc[mt][3][r];
        float cv = fsig(zf)*c01[mt][r] + fsig(zi)*ftanh(zg);
        c01[mt][r] = cv;
        float hv = fsig(zo)*ftanh(cv);
        unsigned short hi = bf16rne(hv);
        hh_[mt][r] = hi;
        hl_[mt][r] = bf16rne(hv - bf2f(hi));
      }
    }
    if (t > 0) __syncthreads();        // all reads of h(t) complete before overwrite
    #pragma unroll
    for (int mt=0;mt<2;mt++){
      #pragma unroll
      for (int r=0;r<4;r++){
        int m = mt*16 + lg*4 + r;
        int u = wv*16 + l15;
        hhi[m*PADU + u] = hh_[mt][r];
        hlo[m*PADU + u] = hl_[mt][r];
      }
    }
    __syncthreads();
  }
  // ---- epilogue: rebuild catf in (now-dead) whhl, then fused MLP ----
  float* catf = (float*)whhl;          // 32 x PADC fp32 (25 KB << 128 KB)
  {
    const size_t grow = ((size_t)(b*TT+TT-1)*NN + n0)*CC;
    for (int i = tid; i < 32*192; i += 512){
      int m = i / 192, k = i - m*192;
      float v;
      if (k < 128) v = bf2f(hhi[m*PADU + k]) + bf2f(hlo[m*PADU + k]);
      else {
        size_t gi = grow + (size_t)m*CC + (k-128);
        v = bf2f(ghi[gi]) + bf2f(glo[gi]);
      }
      catf[m*PADC + k] = v;
    }
  }
  __syncthreads();
  const int u = tid & 127;
  const int rg = tid >> 7;
  float fa[8];
  #pragma unroll
  for (int r=0;r<8;r++) fa[r] = bfv[u];
  for (int k4=0;k4<48;k4++){
    float4 wf = *(const float4*)&WfT[u*192 + k4*4];
    #pragma unroll
    for (int r=0;r<8;r++){
      float4 cv = *(const float4*)&catf[(rg*8+r)*PADC + k4*4];
      fa[r] = fmaf(cv.x,wf.x,fmaf(cv.y,wf.y,fmaf(cv.z,wf.z,fmaf(cv.w,wf.w,fa[r]))));
    }
  }
  float wo = Wo[u];
  #pragma unroll
  for (int r=0;r<8;r++) fa[r] = fmaxf(fa[r], 0.f) * wo;
  __syncthreads();                     // all catf/hbuf reads done before red overwrite
  float* red = (float*)hbuf;           // 16 KB fits in 17.4 KB
  #pragma unroll
  for (int r=0;r<8;r++) red[(rg*8+r)*FHN + u] = fa[r];
  __syncthreads();
  for (int s=64;s>=1;s>>=1){
    if (u < s){
      #pragma unroll
      for (int r=0;r<8;r++) red[(rg*8+r)*FHN + u] += red[(rg*8+r)*FHN + u + s];
    }
    __syncthreads();
  }
  if (u == 0){
    #pragma unroll
    for (int r=0;r<8;r++) out[r0 + rg*8 + r] = red[(rg*8+r)*FHN] + bo[0];
  }
}

// ---------------- launch ----------------
extern "C" void kernel_launch(void* const* d_in, const int* in_sizes, int n_in,
                              void* d_out, int out_size, void* d_ws, size_t ws_size,
                              hipStream_t stream) {
  const float* x_seq  = (const float*)d_in[0];
  const float* W1     = (const float*)d_in[1];
  const float* a_src1 = (const float*)d_in[2];
  const float* a_dst1 = (const float*)d_in[3];
  const float* b1     = (const float*)d_in[4];
  const float* W2     = (const float*)d_in[5];
  const float* a_src2 = (const float*)d_in[6];
  const float* a_dst2 = (const float*)d_in[7];
  const float* b2     = (const float*)d_in[8];
  const float* W_ih   = (const float*)d_in[9];
  const float* W_hh   = (const float*)d_in[10];
  const float* b_ih   = (const float*)d_in[11];
  const float* b_hh   = (const float*)d_in[12];
  const float* Wf     = (const float*)d_in[13];
  const float* bfv    = (const float*)d_in[14];
  const float* Wo     = (const float*)d_in[15];
  const float* bo     = (const float*)d_in[16];
  const int*   ei     = (const int*)d_in[17];
  const int* e_src = ei;
  const int* e_dst = ei + EE;
  float* out = (float*)d_out;

  char* w = (char*)d_ws;
  auto alloc = [&](size_t bytes)->char*{
    char* p = w; w += (bytes + 255) & ~(size_t)255; return p;
  };
  float* als   = (float*)alloc((size_t)BT*NN*HH*4);
  float* ald   = (float*)alloc((size_t)BT*NN*HH*4);
  float* gat1  = (float*)alloc((size_t)BT*NN*CC*4);                 // layer1 out fp32
  unsigned short* ghi = (unsigned short*)alloc((size_t)BT*NN*CC*2); // layer2 out bf16-hi
  unsigned short* glo = (unsigned short*)alloc((size_t)BT*NN*CC*2); // layer2 out bf16-lo
  unsigned short* wfh = (unsigned short*)alloc((size_t)12288*8*2);  // LSTM W frag hi
  unsigned short* wfl = (unsigned short*)alloc((size_t)12288*8*2);  // LSTM W frag lo
  unsigned short* wb1h = (unsigned short*)alloc((size_t)1024*8*2);  // GAT1 Wb frag hi
  unsigned short* wb1l = (unsigned short*)alloc((size_t)1024*8*2);
  unsigned short* wb2h = (unsigned short*)alloc((size_t)2048*8*2);  // GAT2 Wb frag hi
  unsigned short* wb2l = (unsigned short*)alloc((size_t)2048*8*2);
  float* WfT   = (float*)alloc((size_t)128*192*4);
  float* wt    = (float*)alloc((size_t)768*4);
  int* cnt     = (int*)alloc((size_t)2*NN*4);
  int* cur     = cnt + NN;
  int* ptr     = (int*)alloc((size_t)(NN+1)*4);
  int* idxa    = (int*)alloc((size_t)NE*4);
  int* srcs    = (int*)alloc((size_t)NE*4);

  // merged prep
  k_prep<<<(2*NN+768+12288+24576+1024+2048+255)/256, 256, 0, stream>>>(
      cnt, W1, a_src1, a_dst1, W2, a_src2, a_dst2, wt, W_ih, W_hh, wfh, wfl, Wf, WfT,
      wb1h, wb1l, wb2h, wb2l);
  // CSR build (same graph for all 16 instances)
  k_count<<<(NE+255)/256, 256, 0, stream>>>(e_dst, cnt);
  k_scan<<<1, 1024, 0, stream>>>(cnt, ptr);
  k_scatter<<<(NE+255)/256, 256, 0, stream>>>(e_dst, ptr, cur, idxa);
  k_sortseg<<<(NN+255)/256, 256, 0, stream>>>(ptr, idxa, e_src, srcs);

  // GAT layer 1 (32-dim x-space agg, 4-edge unrolled gather)
  k_coef3<32><<<(BT*NN+255)/256, 256, 0, stream>>>(x_seq, wt, wt+128, als, ald);
  k_gatt<32,false><<<4000, 256, 0, stream>>>(ptr, srcs, als, ald, x_seq, wb1h, wb1l, b1,
                                             gat1, nullptr, nullptr);
  // GAT layer 2 (64-dim) — emits bf16-split g only
  k_coef3<64><<<(BT*NN+255)/256, 256, 0, stream>>>(gat1, wt+256, wt+512, als, ald);
  k_gatt<64,true><<<4000, 256, 0, stream>>>(ptr, srcs, als, ald, gat1, wb2h, wb2l, b2,
                                            nullptr, ghi, glo);

  // MFMA LSTM + fused output MLP (WhhHI LDS-resident)
  k_lstm11<<<BB*NN/32, 512, 0, stream>>>(ghi, glo, wfh, wfl, b_ih, b_hh, WfT, bfv, Wo, bo, out);
}